// Round 9
// baseline (800.242 us; speedup 1.0000x reference)
//
#include <hip/hip_runtime.h>
#include <hip/hip_bf16.h>

#define LR 0.01f

typedef __attribute__((ext_vector_type(8))) short short8;
typedef __attribute__((ext_vector_type(4))) float float4v;
typedef __attribute__((ext_vector_type(4))) unsigned short ushort4v;

static __device__ __forceinline__ unsigned short f2bf(float x) {
    union { float f; unsigned u; } un; un.f = x;
    unsigned r = un.u + 0x7fffu + ((un.u >> 16) & 1u);   // RNE
    return (unsigned short)(r >> 16);
}
static __device__ __forceinline__ float bf2f(unsigned short x) {
    union { float f; unsigned u; } un; un.u = ((unsigned)x) << 16;
    return un.f;
}

// Fragment-major index for K/Q: element K[b][c*64 + tt*16 + lm][ks*32 + qd*8 + e]
// stored at ((((b*32+c)*4 + tt)*32 + ks)*64 + qd*16 + lm)*8 + e, so a wave's
// MFMA fragment load is base + lane*16B (lane = qd*16+lm) -> fully coalesced.
static __device__ __forceinline__ size_t kq_frag_idx(int b, int s, int j) {
    // s = within-batch token, j = dim
    return ((((size_t)(b * 32 + (s >> 6)) * 4 + ((s >> 4) & 3)) * 32 + (j >> 5)) * 512)
         + (size_t)(((j >> 3) & 3) * 16 + (s & 15)) * 8 + (j & 7);
}

// ---------------------------------------------------------------------------
// Phase 0: one-shot fp32 -> bf16 cast of A and thetas (verified round 8).
// ---------------------------------------------------------------------------
__global__ __launch_bounds__(256) void cast_all(
    const float* __restrict__ A,
    const float* __restrict__ T0, const float* __restrict__ T1,
    const float* __restrict__ T2,
    unsigned short* __restrict__ Ab,
    unsigned short* __restrict__ Tb)
{
    const int bid = blockIdx.x;
    const int tid = threadIdx.x;
    if (bid < 2048) {
        for (int i = bid * 256 + tid; i < 2097152; i += 2048 * 256) {
            const float4v* s = (const float4v*)(A + (size_t)i * 8);
            float4v a = s[0], b = s[1];
            short8 o;
#pragma unroll
            for (int j = 0; j < 4; ++j) { o[j] = (short)f2bf(a[j]); o[j + 4] = (short)f2bf(b[j]); }
            *(short8*)(Ab + (size_t)i * 8) = o;
        }
    } else {
        const int base = bid - 2048;
        const int t = base >> 7;
        const int lb = base & 127;
        const float* S = (t == 0) ? T0 : (t == 1 ? T1 : T2);
        unsigned short* D = Tb + (size_t)t * 1048576;
        for (int i = lb * 256 + tid; i < 131072; i += 128 * 256) {
            const float4v* s = (const float4v*)(S + (size_t)i * 8);
            float4v a = s[0], b = s[1];
            short8 o;
#pragma unroll
            for (int j = 0; j < 4; ++j) { o[j] = (short)f2bf(a[j]); o[j + 4] = (short)f2bf(b[j]); }
            *(short8*)(D + (size_t)i * 8) = o;
        }
    }
}

// ---------------------------------------------------------------------------
// Phase 1 (fast path): projections from pre-cast bf16. K/Q written in
// FRAGMENT-MAJOR layout (kq_frag_idx); V row-major; Kt as before.
// ---------------------------------------------------------------------------
__global__ __launch_bounds__(256) void proj_gemm_bf(
    const unsigned short* __restrict__ A,    // bf16 [16384][1024]
    const unsigned short* __restrict__ Tb,   // bf16 [3][1024][1024]
    unsigned short* __restrict__ Kf,
    unsigned short* __restrict__ Vp,
    unsigned short* __restrict__ Qf,
    unsigned short* __restrict__ ktw)
{
    __shared__ unsigned short As[64][40];
    __shared__ unsigned short Bs[3][64][40];

    const int tid  = threadIdx.x;
    const int lane = tid & 63;
    const int wave = tid >> 6;
    const int m0 = blockIdx.x * 64;
    const int n0 = blockIdx.y * 64;
    const int srow = tid >> 2;
    const int sseg = (tid & 3) * 8;
    const int mrow = lane & 15;
    const int quad = lane >> 4;

    float4v acc[3][4];
#pragma unroll
    for (int z = 0; z < 3; ++z)
#pragma unroll
        for (int i = 0; i < 4; ++i) acc[z][i] = (float4v){0.f, 0.f, 0.f, 0.f};

    const unsigned short* apBase = A  + (size_t)(m0 + srow) * 1024 + sseg;
    const unsigned short* bp0 = Tb               + (size_t)(n0 + srow) * 1024 + sseg;
    const unsigned short* bp1 = Tb + 1048576     + (size_t)(n0 + srow) * 1024 + sseg;
    const unsigned short* bp2 = Tb + 2 * 1048576 + (size_t)(n0 + srow) * 1024 + sseg;

    for (int kt = 0; kt < 1024; kt += 32) {
        short8 av = *(const short8*)(apBase + kt);
        short8 b0 = *(const short8*)(bp0 + kt);
        short8 b1 = *(const short8*)(bp1 + kt);
        short8 b2 = *(const short8*)(bp2 + kt);

        __syncthreads();
        *(short8*)&As[srow][sseg]    = av;
        *(short8*)&Bs[0][srow][sseg] = b0;
        *(short8*)&Bs[1][srow][sseg] = b1;
        *(short8*)&Bs[2][srow][sseg] = b2;
        __syncthreads();

        short8 af = *(const short8*)&As[16 * wave + mrow][quad * 8];
#pragma unroll
        for (int z = 0; z < 3; ++z)
#pragma unroll
            for (int nb = 0; nb < 4; ++nb) {
                short8 bfr = *(const short8*)&Bs[z][16 * nb + mrow][quad * 8];
                acc[z][nb] = __builtin_amdgcn_mfma_f32_16x16x32_bf16(af, bfr, acc[z][nb], 0, 0, 0);
            }
    }

    const int batch = m0 >> 11;
    const int s0    = m0 & 2047;
#pragma unroll
    for (int nb = 0; nb < 4; ++nb) {
#pragma unroll
        for (int r = 0; r < 4; ++r) {
            int tl = 16 * wave + quad * 4 + r;     // token-local
            int jl = 16 * nb + mrow;               // dim-local
            int s = s0 + tl;                       // within-batch token
            int j = n0 + jl;                       // dim
            size_t fK = kq_frag_idx(batch, s, j);
            Kf[fK] = f2bf(acc[0][nb][r]);
            Qf[fK] = f2bf(acc[2][nb][r]);
            Vp[(size_t)(m0 + tl) * 1024 + j] = f2bf(acc[1][nb][r]);
            ktw[(size_t)batch * 2097152 + (size_t)j * 2048 + s] = f2bf(-LR * acc[0][nb][r]);
        }
    }
}

// ---------------------------------------------------------------------------
// Phase 1 (fallback): fp32-input proj, same new store layout.
// ---------------------------------------------------------------------------
__global__ __launch_bounds__(256) void proj_gemm(
    const float* __restrict__ A,
    const float* __restrict__ T0, const float* __restrict__ T1,
    const float* __restrict__ T2,
    unsigned short* __restrict__ Kf,
    unsigned short* __restrict__ Vp,
    unsigned short* __restrict__ Qf,
    unsigned short* __restrict__ ktw)
{
    __shared__ unsigned short As[64][40];
    __shared__ unsigned short Bs[3][64][40];

    const int tid  = threadIdx.x;
    const int lane = tid & 63;
    const int wave = tid >> 6;
    const int m0 = blockIdx.x * 64;
    const int n0 = blockIdx.y * 64;
    const int srow = tid >> 2;
    const int sseg = (tid & 3) * 8;
    const int mrow = lane & 15;
    const int quad = lane >> 4;

    float4v acc[3][4];
#pragma unroll
    for (int z = 0; z < 3; ++z)
#pragma unroll
        for (int i = 0; i < 4; ++i) acc[z][i] = (float4v){0.f, 0.f, 0.f, 0.f};

    const float* apBase = A  + (size_t)(m0 + srow) * 1024 + sseg;
    const float* bp0 = T0 + (size_t)(n0 + srow) * 1024 + sseg;
    const float* bp1 = T1 + (size_t)(n0 + srow) * 1024 + sseg;
    const float* bp2 = T2 + (size_t)(n0 + srow) * 1024 + sseg;

    for (int kt = 0; kt < 1024; kt += 32) {
        float4v av0 = ((const float4v*)(apBase + kt))[0];
        float4v av1 = ((const float4v*)(apBase + kt))[1];
        float4v b00 = ((const float4v*)(bp0 + kt))[0], b01 = ((const float4v*)(bp0 + kt))[1];
        float4v b10 = ((const float4v*)(bp1 + kt))[0], b11 = ((const float4v*)(bp1 + kt))[1];
        float4v b20 = ((const float4v*)(bp2 + kt))[0], b21 = ((const float4v*)(bp2 + kt))[1];

        __syncthreads();
        short8 apk, bpk0, bpk1, bpk2;
#pragma unroll
        for (int i = 0; i < 4; ++i) {
            apk[i]      = (short)f2bf(av0[i]);
            apk[i + 4]  = (short)f2bf(av1[i]);
            bpk0[i]     = (short)f2bf(b00[i]);
            bpk0[i + 4] = (short)f2bf(b01[i]);
            bpk1[i]     = (short)f2bf(b10[i]);
            bpk1[i + 4] = (short)f2bf(b11[i]);
            bpk2[i]     = (short)f2bf(b20[i]);
            bpk2[i + 4] = (short)f2bf(b21[i]);
        }
        *(short8*)&As[srow][sseg]    = apk;
        *(short8*)&Bs[0][srow][sseg] = bpk0;
        *(short8*)&Bs[1][srow][sseg] = bpk1;
        *(short8*)&Bs[2][srow][sseg] = bpk2;
        __syncthreads();

        short8 af = *(const short8*)&As[16 * wave + mrow][quad * 8];
#pragma unroll
        for (int z = 0; z < 3; ++z)
#pragma unroll
            for (int nb = 0; nb < 4; ++nb) {
                short8 bfr = *(const short8*)&Bs[z][16 * nb + mrow][quad * 8];
                acc[z][nb] = __builtin_amdgcn_mfma_f32_16x16x32_bf16(af, bfr, acc[z][nb], 0, 0, 0);
            }
    }

    const int batch = m0 >> 11;
    const int s0    = m0 & 2047;
#pragma unroll
    for (int nb = 0; nb < 4; ++nb) {
#pragma unroll
        for (int r = 0; r < 4; ++r) {
            int tl = 16 * wave + quad * 4 + r;
            int jl = 16 * nb + mrow;
            int s = s0 + tl;
            int j = n0 + jl;
            size_t fK = kq_frag_idx(batch, s, j);
            Kf[fK] = f2bf(acc[0][nb][r]);
            Qf[fK] = f2bf(acc[2][nb][r]);
            Vp[(size_t)(m0 + tl) * 1024 + j] = f2bf(acc[1][nb][r]);
            ktw[(size_t)batch * 2097152 + (size_t)j * 2048 + s] = f2bf(-LR * acc[0][nb][r]);
        }
    }
}

// ---------------------------------------------------------------------------
// Phase 2: Linv/Mp precompute (same math); K/Q now read from frag layout —
// every fragment load is base + lane*16B (coalesced). Values identical.
// ---------------------------------------------------------------------------
__global__ __launch_bounds__(256) void precomp(
    const unsigned short* __restrict__ K,    // frag-major
    const unsigned short* __restrict__ Q,    // frag-major
    unsigned short* __restrict__ LinvG,
    unsigned short* __restrict__ MpG)
{
    __shared__ float Skk[64][68];
    __shared__ float Sqk[64][68];
    __shared__ unsigned short Lb[64][72];
    __shared__ unsigned short Xa[64][72];

    const int tid = threadIdx.x;
    const int lane = tid & 63;
    const int w = tid >> 6;
    const int lm = lane & 15;
    const int quad = lane >> 4;
    const int batch = blockIdx.x >> 5;
    const int c = blockIdx.x & 31;
    const size_t blk = (size_t)batch * 32 + c;

    float4v kk[4], qk[4];
#pragma unroll
    for (int i = 0; i < 4; ++i) { kk[i] = (float4v){0,0,0,0}; qk[i] = (float4v){0,0,0,0}; }

    // frag bases: per (chunk, token-tile) block of 32ks*512 = 16384 shorts
    const unsigned short* aKp = K + (blk * 4 + w) * 16384 + (size_t)lane * 8;
    const unsigned short* aQp = Q + (blk * 4 + w) * 16384 + (size_t)lane * 8;
#pragma unroll 4
    for (int ks = 0; ks < 32; ++ks) {
        short8 aK = *(const short8*)(aKp + ks * 512);
        short8 aQ = *(const short8*)(aQp + ks * 512);
#pragma unroll
        for (int nb = 0; nb < 4; ++nb) {
            short8 bK = *(const short8*)(K + (blk * 4 + nb) * 16384 + (size_t)lane * 8 + ks * 512);
            kk[nb] = __builtin_amdgcn_mfma_f32_16x16x32_bf16(aK, bK, kk[nb], 0, 0, 0);
            qk[nb] = __builtin_amdgcn_mfma_f32_16x16x32_bf16(aQ, bK, qk[nb], 0, 0, 0);
        }
    }
#pragma unroll
    for (int nb = 0; nb < 4; ++nb)
#pragma unroll
        for (int r = 0; r < 4; ++r) {
            Skk[w * 16 + quad * 4 + r][nb * 16 + lm] = kk[nb][r];
            Sqk[w * 16 + quad * 4 + r][nb * 16 + lm] = qk[nb][r];
        }
    __syncthreads();

    const float c1 = 2.0f * LR / 1024.0f;
#pragma unroll
    for (int e = 0; e < 16; ++e) {
        int idx = tid * 16 + e;
        int t = idx >> 6, i = idx & 63;
        float a = (i < t) ? c1 * (Skk[t][i] + 1.0f) : 0.0f;
        Lb[t][i] = f2bf(a);
        Xa[i][t] = f2bf(((i == t) ? 1.0f : 0.0f) - a);
        float mq = (i <= t) ? -LR * (Sqk[t][i] + 1.0f) : 0.0f;
        MpG[blk * 4096 + (size_t)t * 64 + i] = f2bf(mq);
    }
    __syncthreads();

    short8 afL0 = *(const short8*)&Lb[w * 16 + lm][quad * 8];
    short8 afL1 = *(const short8*)&Lb[w * 16 + lm][32 + quad * 8];
    float4v p[4];
#pragma unroll
    for (int nb = 0; nb < 4; ++nb) {
        p[nb] = (float4v){0,0,0,0};
        short8 b0f = *(const short8*)&Xa[nb * 16 + lm][quad * 8];
        short8 b1f = *(const short8*)&Xa[nb * 16 + lm][32 + quad * 8];
        p[nb] = __builtin_amdgcn_mfma_f32_16x16x32_bf16(afL0, b0f, p[nb], 0, 0, 0);
        p[nb] = __builtin_amdgcn_mfma_f32_16x16x32_bf16(afL1, b1f, p[nb], 0, 0, 0);
    }
    __syncthreads();
#pragma unroll
    for (int nb = 0; nb < 4; ++nb)
#pragma unroll
        for (int r = 0; r < 4; ++r) {
            int ii = nb * 16 + lm, tt = w * 16 + quad * 4 + r;
            Xa[ii][tt] = f2bf(((ii == tt) ? 1.0f : 0.0f) - p[nb][r]);
        }
    __syncthreads();

#pragma unroll
    for (int nb = 0; nb < 4; ++nb) {
        p[nb] = (float4v){0,0,0,0};
        short8 b0f = *(const short8*)&Xa[nb * 16 + lm][quad * 8];
        short8 b1f = *(const short8*)&Xa[nb * 16 + lm][32 + quad * 8];
        p[nb] = __builtin_amdgcn_mfma_f32_16x16x32_bf16(afL0, b0f, p[nb], 0, 0, 0);
        p[nb] = __builtin_amdgcn_mfma_f32_16x16x32_bf16(afL1, b1f, p[nb], 0, 0, 0);
    }
#pragma unroll
    for (int nb = 0; nb < 4; ++nb)
#pragma unroll
        for (int r = 0; r < 4; ++r) {
            int ii = nb * 16 + lm, tt = w * 16 + quad * 4 + r;
            LinvG[blk * 4096 + (size_t)tt * 64 + ii] =
                f2bf(((ii == tt) ? 1.0f : 0.0f) - p[nb][r]);
        }
}

// ---------------------------------------------------------------------------
// Phase 3: role-split ttt (verified round 7). Only change: (b)'s X loads read
// the frag-major K/Q layout (base + lane*16B, coalesced). Same values.
// ---------------------------------------------------------------------------
__global__ __launch_bounds__(512, 2) void ttt_chunk(
    const unsigned short* __restrict__ K,    // frag-major
    const unsigned short* __restrict__ V,    // row-major
    const unsigned short* __restrict__ Q,    // frag-major
    const unsigned short* __restrict__ Kt,
    const unsigned short* __restrict__ Linv,
    const unsigned short* __restrict__ Mp,
    const float* __restrict__ W0,
    const float* __restrict__ b0,
    float* __restrict__ out)
{
    __shared__ unsigned short Wb[32][1032];   // bf16 W mirror (66 KB)
    __shared__ unsigned short Ut[32][72];
    __shared__ unsigned short Gt[32][72];
    __shared__ __align__(16) float bb[32];

    const int tid  = threadIdx.x;
    const int lane = tid & 63;
    const int w    = tid >> 6;          // wave 0..7
    const int g    = w & 3;             // token-group
    const int role = w >> 2;            // 0 = U-producer (K), 1 = O-producer (Q)
    const int lm   = lane & 15;
    const int quad = lane >> 4;
    const int batch = blockIdx.x & 7;
    const int r0    = (blockIdx.x >> 3) * 32;   // row-slab base (32 rows)

    float4v acc_w[2][8];
#pragma unroll
    for (int rs2 = 0; rs2 < 2; ++rs2)
#pragma unroll
        for (int i = 0; i < 8; ++i) {
            int nt = w + 8 * i;
#pragma unroll
            for (int r = 0; r < 4; ++r)
                acc_w[rs2][i][r] =
                    W0[(size_t)(r0 + rs2 * 16 + quad * 4 + r) * 1024 + nt * 16 + lm];
        }
    if (tid < 32) bb[tid] = b0[r0 + tid];

    const size_t tokBase = (size_t)batch * 2048;
    const unsigned short* KtB = Kt + (size_t)batch * 2097152;
    const unsigned short* X = role ? Q : K;     // this wave's (b) operand stream
    const float sc = 2.0f / 1024.0f;

    for (int c = 0; c < 32; ++c) {
        // (a) dump fp32 W regs -> bf16 LDS mirror (both halves)
#pragma unroll
        for (int rs2 = 0; rs2 < 2; ++rs2)
#pragma unroll
            for (int i = 0; i < 8; ++i) {
                int nt = w + 8 * i;
#pragma unroll
                for (int r = 0; r < 4; ++r)
                    Wb[rs2 * 16 + quad * 4 + r][nt * 16 + lm] = f2bf(acc_w[rs2][i][r]);
            }
        __syncthreads();   // B1: Wb ready

        // (b) role-split contraction; X loads are frag-major (coalesced)
        const size_t tok = tokBase + c * 64 + g * 16 + lm;   // for V / out
        const unsigned short* xRow =
            X + (((size_t)batch * 32 + c) * 4 + g) * 16384 + (size_t)lane * 8;
        const unsigned short* wRow0 = &Wb[lm][quad * 8];
        const unsigned short* wRow1 = &Wb[16 + lm][quad * 8];
        float4v a0v = (float4v){0,0,0,0};
        float4v a1v = (float4v){0,0,0,0};
#pragma unroll 8
        for (int ks = 0; ks < 32; ++ks) {
            short8 xf  = *(const short8*)(xRow + ks * 512);
            short8 af0 = *(const short8*)(wRow0 + ks * 32);
            short8 af1 = *(const short8*)(wRow1 + ks * 32);
            a0v = __builtin_amdgcn_mfma_f32_16x16x32_bf16(af0, xf, a0v, 0, 0, 0);
            a1v = __builtin_amdgcn_mfma_f32_16x16x32_bf16(af1, xf, a1v, 0, 0, 0);
        }
        float4v bval0 = *(const float4v*)&bb[quad * 4];
        float4v bval1 = *(const float4v*)&bb[16 + quad * 4];
        if (role == 0) {
            ushort4v vv0 = *(const ushort4v*)(V + tok * 1024 + r0 + quad * 4);
            ushort4v vv1 = *(const ushort4v*)(V + tok * 1024 + r0 + 16 + quad * 4);
#pragma unroll
            for (int r = 0; r < 4; ++r) {
                Ut[quad * 4 + r][g * 16 + lm]      = f2bf(sc * (a0v[r] + bval0[r] - bf2f(vv0[r])));
                Ut[16 + quad * 4 + r][g * 16 + lm] = f2bf(sc * (a1v[r] + bval1[r] - bf2f(vv1[r])));
            }
        }
        __syncthreads();   // B2: Ut ready

        const size_t lbase = ((size_t)(batch * 32 + c)) * 4096 + (size_t)(g * 16 + lm) * 64;

        // (c) G^T: wave (g,role) handles row-half = role
        {
            float4v accG = (float4v){0,0,0,0};
            short8 a0 = *(const short8*)&Ut[role * 16 + lm][quad * 8];
            short8 a1 = *(const short8*)&Ut[role * 16 + lm][32 + quad * 8];
            short8 l0 = *(const short8*)(Linv + lbase + quad * 8);
            short8 l1 = *(const short8*)(Linv + lbase + 32 + quad * 8);
            accG = __builtin_amdgcn_mfma_f32_16x16x32_bf16(a0, l0, accG, 0, 0, 0);
            accG = __builtin_amdgcn_mfma_f32_16x16x32_bf16(a1, l1, accG, 0, 0, 0);
#pragma unroll
            for (int r = 0; r < 4; ++r)
                Gt[role * 16 + quad * 4 + r][g * 16 + lm] = f2bf(accG[r]);
        }
        __syncthreads();   // B3: Gt ready

        short8 agA0 = *(const short8*)&Gt[lm][quad * 8];
        short8 agA1 = *(const short8*)&Gt[lm][32 + quad * 8];
        short8 agB0 = *(const short8*)&Gt[16 + lm][quad * 8];
        short8 agB1 = *(const short8*)&Gt[16 + lm][32 + quad * 8];

        // (d) role-1 waves: O += Gt . Mp + b ; store both row halves
        if (role == 1) {
            short8 m0f = *(const short8*)(Mp + lbase + quad * 8);
            short8 m1f = *(const short8*)(Mp + lbase + 32 + quad * 8);
            a0v = __builtin_amdgcn_mfma_f32_16x16x32_bf16(agA0, m0f, a0v, 0, 0, 0);
            a0v = __builtin_amdgcn_mfma_f32_16x16x32_bf16(agA1, m1f, a0v, 0, 0, 0);
            a1v = __builtin_amdgcn_mfma_f32_16x16x32_bf16(agB0, m0f, a1v, 0, 0, 0);
            a1v = __builtin_amdgcn_mfma_f32_16x16x32_bf16(agB1, m1f, a1v, 0, 0, 0);
            float4v ov0, ov1;
#pragma unroll
            for (int r = 0; r < 4; ++r) { ov0[r] = a0v[r] + bval0[r]; ov1[r] = a1v[r] + bval1[r]; }
            *(float4v*)(out + tok * 1024 + r0 + quad * 4)      = ov0;
            *(float4v*)(out + tok * 1024 + r0 + 16 + quad * 4) = ov1;
        }

        // (e) W += Gt . Kt-contraction, inline Kt loads
#pragma unroll
        for (int i = 0; i < 8; ++i) {
            int nt = w + 8 * i;
            const unsigned short* kp = KtB + (size_t)(nt * 16 + lm) * 2048 + c * 64;
            short8 kb0 = *(const short8*)(kp + quad * 8);
            short8 kb1 = *(const short8*)(kp + 32 + quad * 8);
            acc_w[0][i] = __builtin_amdgcn_mfma_f32_16x16x32_bf16(agA0, kb0, acc_w[0][i], 0, 0, 0);
            acc_w[0][i] = __builtin_amdgcn_mfma_f32_16x16x32_bf16(agA1, kb1, acc_w[0][i], 0, 0, 0);
            acc_w[1][i] = __builtin_amdgcn_mfma_f32_16x16x32_bf16(agB0, kb0, acc_w[1][i], 0, 0, 0);
            acc_w[1][i] = __builtin_amdgcn_mfma_f32_16x16x32_bf16(agB1, kb1, acc_w[1][i], 0, 0, 0);
        }

        // (f) bias update: wave 0, 2 lanes per row + shuffle reduce
        if (w == 0) {
            int row = lane >> 1, part = lane & 1;
            float s = 0.f;
#pragma unroll
            for (int t = 0; t < 32; ++t) s += bf2f(Gt[row][part * 32 + t]);
            s += __shfl_xor(s, 1);
            if (part == 0) bb[row] -= LR * s;
        }
        __syncthreads();   // B4: end-of-chunk
    }
}

// ---------------------------------------------------------------------------
extern "C" void kernel_launch(void* const* d_in, const int* in_sizes, int n_in,
                              void* d_out, int out_size, void* d_ws, size_t ws_size,
                              hipStream_t stream) {
    (void)in_sizes; (void)n_in; (void)out_size;
    const float* in_seq = (const float*)d_in[0];
    const float* thK    = (const float*)d_in[1];
    const float* thV    = (const float*)d_in[2];
    const float* thQ    = (const float*)d_in[3];
    const float* W0     = (const float*)d_in[4];
    const float* b0     = (const float*)d_in[5];
    float* out = (float*)d_out;

    unsigned short* ws = (unsigned short*)d_ws;
    unsigned short* Kf   = ws;                                  // 32 MB (frag-major)
    unsigned short* Vp   = ws + (size_t)16384 * 1024;           // 32 MB (row-major)
    unsigned short* Qf   = ws + (size_t)2 * 16384 * 1024;       // 32 MB (frag-major)
    unsigned short* Ktp  = ws + (size_t)3 * 16384 * 1024;       // 32 MB
    unsigned short* Linv = ws + (size_t)4 * 16384 * 1024;       // 2 MB
    unsigned short* Mpp  = Linv + (size_t)8 * 32 * 4096;        // 2 MB
    unsigned short* Abf  = Mpp + (size_t)8 * 32 * 4096;         // 32 MB (pre-cast A)
    unsigned short* Tbf  = Abf + (size_t)16384 * 1024;          // 6 MB  (pre-cast thetas)

    const size_t need_shorts = (size_t)4 * 16384 * 1024 + 2 * (size_t)8 * 32 * 4096
                             + (size_t)16384 * 1024 + (size_t)3 * 1024 * 1024;

    dim3 g1(16384 / 64, 1024 / 64);
    if (ws_size >= need_shorts * 2) {
        cast_all<<<2432, 256, 0, stream>>>(in_seq, thK, thV, thQ, Abf, Tbf);
        proj_gemm_bf<<<g1, 256, 0, stream>>>(Abf, Tbf, Kf, Vp, Qf, Ktp);
    } else {
        proj_gemm<<<g1, 256, 0, stream>>>(in_seq, thK, thV, thQ, Kf, Vp, Qf, Ktp);
    }

    precomp<<<256, 256, 0, stream>>>(Kf, Qf, Linv, Mpp);

    ttt_chunk<<<256, 512, 0, stream>>>(Kf, Vp, Qf, Ktp, Linv, Mpp, W0, b0, out);
}

// Round 10
// 667.021 us; speedup vs baseline: 1.1997x; 1.1997x over previous
//
#include <hip/hip_runtime.h>
#include <hip/hip_bf16.h>

#define LR 0.01f

typedef __attribute__((ext_vector_type(8))) short short8;
typedef __attribute__((ext_vector_type(4))) float float4v;
typedef __attribute__((ext_vector_type(4))) unsigned short ushort4v;

static __device__ __forceinline__ unsigned short f2bf(float x) {
    union { float f; unsigned u; } un; un.f = x;
    unsigned r = un.u + 0x7fffu + ((un.u >> 16) & 1u);   // RNE
    return (unsigned short)(r >> 16);
}
static __device__ __forceinline__ float bf2f(unsigned short x) {
    union { float f; unsigned u; } un; un.u = ((unsigned)x) << 16;
    return un.f;
}

// Fragment-major index for K/Q (verified round 9): element K[b][s][j] at
// ((((b*32+c)*4+tt)*32+ks)*512) + (qd*16+lm)*8 + e  with c=s>>6, tt=(s>>4)&3,
// lm=s&15, ks=j>>5, qd=(j>>3)&3, e=j&7.
static __device__ __forceinline__ size_t kq_frag_idx(int b, int s, int j) {
    return ((((size_t)(b * 32 + (s >> 6)) * 4 + ((s >> 4) & 3)) * 32 + (j >> 5)) * 512)
         + (size_t)(((j >> 3) & 3) * 16 + (s & 15)) * 8 + (j & 7);
}

// ---------------------------------------------------------------------------
// Phase 0: one-shot fp32 -> bf16 cast of A and thetas (verified round 8).
// ---------------------------------------------------------------------------
__global__ __launch_bounds__(256) void cast_all(
    const float* __restrict__ A,
    const float* __restrict__ T0, const float* __restrict__ T1,
    const float* __restrict__ T2,
    unsigned short* __restrict__ Ab,
    unsigned short* __restrict__ Tb)
{
    const int bid = blockIdx.x;
    const int tid = threadIdx.x;
    if (bid < 2048) {
        for (int i = bid * 256 + tid; i < 2097152; i += 2048 * 256) {
            const float4v* s = (const float4v*)(A + (size_t)i * 8);
            float4v a = s[0], b = s[1];
            short8 o;
#pragma unroll
            for (int j = 0; j < 4; ++j) { o[j] = (short)f2bf(a[j]); o[j + 4] = (short)f2bf(b[j]); }
            *(short8*)(Ab + (size_t)i * 8) = o;
        }
    } else {
        const int base = bid - 2048;
        const int t = base >> 7;
        const int lb = base & 127;
        const float* S = (t == 0) ? T0 : (t == 1 ? T1 : T2);
        unsigned short* D = Tb + (size_t)t * 1048576;
        for (int i = lb * 256 + tid; i < 131072; i += 128 * 256) {
            const float4v* s = (const float4v*)(S + (size_t)i * 8);
            float4v a = s[0], b = s[1];
            short8 o;
#pragma unroll
            for (int j = 0; j < 4; ++j) { o[j] = (short)f2bf(a[j]); o[j + 4] = (short)f2bf(b[j]); }
            *(short8*)(D + (size_t)i * 8) = o;
        }
    }
}

// ---------------------------------------------------------------------------
// Phase 1 (fast path): projections from pre-cast bf16 (verified round 9).
// K/Q stored fragment-major; V row-major; Kt as before.
// ---------------------------------------------------------------------------
__global__ __launch_bounds__(256) void proj_gemm_bf(
    const unsigned short* __restrict__ A,    // bf16 [16384][1024]
    const unsigned short* __restrict__ Tb,   // bf16 [3][1024][1024]
    unsigned short* __restrict__ Kf,
    unsigned short* __restrict__ Vp,
    unsigned short* __restrict__ Qf,
    unsigned short* __restrict__ ktw)
{
    __shared__ unsigned short As[64][40];
    __shared__ unsigned short Bs[3][64][40];

    const int tid  = threadIdx.x;
    const int lane = tid & 63;
    const int wave = tid >> 6;
    const int m0 = blockIdx.x * 64;
    const int n0 = blockIdx.y * 64;
    const int srow = tid >> 2;
    const int sseg = (tid & 3) * 8;
    const int mrow = lane & 15;
    const int quad = lane >> 4;

    float4v acc[3][4];
#pragma unroll
    for (int z = 0; z < 3; ++z)
#pragma unroll
        for (int i = 0; i < 4; ++i) acc[z][i] = (float4v){0.f, 0.f, 0.f, 0.f};

    const unsigned short* apBase = A  + (size_t)(m0 + srow) * 1024 + sseg;
    const unsigned short* bp0 = Tb               + (size_t)(n0 + srow) * 1024 + sseg;
    const unsigned short* bp1 = Tb + 1048576     + (size_t)(n0 + srow) * 1024 + sseg;
    const unsigned short* bp2 = Tb + 2 * 1048576 + (size_t)(n0 + srow) * 1024 + sseg;

    for (int kt = 0; kt < 1024; kt += 32) {
        short8 av = *(const short8*)(apBase + kt);
        short8 b0 = *(const short8*)(bp0 + kt);
        short8 b1 = *(const short8*)(bp1 + kt);
        short8 b2 = *(const short8*)(bp2 + kt);

        __syncthreads();
        *(short8*)&As[srow][sseg]    = av;
        *(short8*)&Bs[0][srow][sseg] = b0;
        *(short8*)&Bs[1][srow][sseg] = b1;
        *(short8*)&Bs[2][srow][sseg] = b2;
        __syncthreads();

        short8 af = *(const short8*)&As[16 * wave + mrow][quad * 8];
#pragma unroll
        for (int z = 0; z < 3; ++z)
#pragma unroll
            for (int nb = 0; nb < 4; ++nb) {
                short8 bfr = *(const short8*)&Bs[z][16 * nb + mrow][quad * 8];
                acc[z][nb] = __builtin_amdgcn_mfma_f32_16x16x32_bf16(af, bfr, acc[z][nb], 0, 0, 0);
            }
    }

    const int batch = m0 >> 11;
    const int s0    = m0 & 2047;
#pragma unroll
    for (int nb = 0; nb < 4; ++nb) {
#pragma unroll
        for (int r = 0; r < 4; ++r) {
            int tl = 16 * wave + quad * 4 + r;     // token-local
            int jl = 16 * nb + mrow;               // dim-local
            int s = s0 + tl;                       // within-batch token
            int j = n0 + jl;                       // dim
            size_t fK = kq_frag_idx(batch, s, j);
            Kf[fK] = f2bf(acc[0][nb][r]);
            Qf[fK] = f2bf(acc[2][nb][r]);
            Vp[(size_t)(m0 + tl) * 1024 + j] = f2bf(acc[1][nb][r]);
            ktw[(size_t)batch * 2097152 + (size_t)j * 2048 + s] = f2bf(-LR * acc[0][nb][r]);
        }
    }
}

// ---------------------------------------------------------------------------
// Phase 1 (fallback): fp32-input proj, same store layout (verified round 9).
// ---------------------------------------------------------------------------
__global__ __launch_bounds__(256) void proj_gemm(
    const float* __restrict__ A,
    const float* __restrict__ T0, const float* __restrict__ T1,
    const float* __restrict__ T2,
    unsigned short* __restrict__ Kf,
    unsigned short* __restrict__ Vp,
    unsigned short* __restrict__ Qf,
    unsigned short* __restrict__ ktw)
{
    __shared__ unsigned short As[64][40];
    __shared__ unsigned short Bs[3][64][40];

    const int tid  = threadIdx.x;
    const int lane = tid & 63;
    const int wave = tid >> 6;
    const int m0 = blockIdx.x * 64;
    const int n0 = blockIdx.y * 64;
    const int srow = tid >> 2;
    const int sseg = (tid & 3) * 8;
    const int mrow = lane & 15;
    const int quad = lane >> 4;

    float4v acc[3][4];
#pragma unroll
    for (int z = 0; z < 3; ++z)
#pragma unroll
        for (int i = 0; i < 4; ++i) acc[z][i] = (float4v){0.f, 0.f, 0.f, 0.f};

    const float* apBase = A  + (size_t)(m0 + srow) * 1024 + sseg;
    const float* bp0 = T0 + (size_t)(n0 + srow) * 1024 + sseg;
    const float* bp1 = T1 + (size_t)(n0 + srow) * 1024 + sseg;
    const float* bp2 = T2 + (size_t)(n0 + srow) * 1024 + sseg;

    for (int kt = 0; kt < 1024; kt += 32) {
        float4v av0 = ((const float4v*)(apBase + kt))[0];
        float4v av1 = ((const float4v*)(apBase + kt))[1];
        float4v b00 = ((const float4v*)(bp0 + kt))[0], b01 = ((const float4v*)(bp0 + kt))[1];
        float4v b10 = ((const float4v*)(bp1 + kt))[0], b11 = ((const float4v*)(bp1 + kt))[1];
        float4v b20 = ((const float4v*)(bp2 + kt))[0], b21 = ((const float4v*)(bp2 + kt))[1];

        __syncthreads();
        short8 apk, bpk0, bpk1, bpk2;
#pragma unroll
        for (int i = 0; i < 4; ++i) {
            apk[i]      = (short)f2bf(av0[i]);
            apk[i + 4]  = (short)f2bf(av1[i]);
            bpk0[i]     = (short)f2bf(b00[i]);
            bpk0[i + 4] = (short)f2bf(b01[i]);
            bpk1[i]     = (short)f2bf(b10[i]);
            bpk1[i + 4] = (short)f2bf(b11[i]);
            bpk2[i]     = (short)f2bf(b20[i]);
            bpk2[i + 4] = (short)f2bf(b21[i]);
        }
        *(short8*)&As[srow][sseg]    = apk;
        *(short8*)&Bs[0][srow][sseg] = bpk0;
        *(short8*)&Bs[1][srow][sseg] = bpk1;
        *(short8*)&Bs[2][srow][sseg] = bpk2;
        __syncthreads();

        short8 af = *(const short8*)&As[16 * wave + mrow][quad * 8];
#pragma unroll
        for (int z = 0; z < 3; ++z)
#pragma unroll
            for (int nb = 0; nb < 4; ++nb) {
                short8 bfr = *(const short8*)&Bs[z][16 * nb + mrow][quad * 8];
                acc[z][nb] = __builtin_amdgcn_mfma_f32_16x16x32_bf16(af, bfr, acc[z][nb], 0, 0, 0);
            }
    }

    const int batch = m0 >> 11;
    const int s0    = m0 & 2047;
#pragma unroll
    for (int nb = 0; nb < 4; ++nb) {
#pragma unroll
        for (int r = 0; r < 4; ++r) {
            int tl = 16 * wave + quad * 4 + r;
            int jl = 16 * nb + mrow;
            int s = s0 + tl;
            int j = n0 + jl;
            size_t fK = kq_frag_idx(batch, s, j);
            Kf[fK] = f2bf(acc[0][nb][r]);
            Qf[fK] = f2bf(acc[2][nb][r]);
            Vp[(size_t)(m0 + tl) * 1024 + j] = f2bf(acc[1][nb][r]);
            ktw[(size_t)batch * 2097152 + (size_t)j * 2048 + s] = f2bf(-LR * acc[0][nb][r]);
        }
    }
}

// ---------------------------------------------------------------------------
// Phase 2: Linv/Mp precompute from frag-major K/Q (verified round 9).
// ---------------------------------------------------------------------------
__global__ __launch_bounds__(256) void precomp(
    const unsigned short* __restrict__ K,    // frag-major
    const unsigned short* __restrict__ Q,    // frag-major
    unsigned short* __restrict__ LinvG,
    unsigned short* __restrict__ MpG)
{
    __shared__ float Skk[64][68];
    __shared__ float Sqk[64][68];
    __shared__ unsigned short Lb[64][72];
    __shared__ unsigned short Xa[64][72];

    const int tid = threadIdx.x;
    const int lane = tid & 63;
    const int w = tid >> 6;
    const int lm = lane & 15;
    const int quad = lane >> 4;
    const int batch = blockIdx.x >> 5;
    const int c = blockIdx.x & 31;
    const size_t blk = (size_t)batch * 32 + c;

    float4v kk[4], qk[4];
#pragma unroll
    for (int i = 0; i < 4; ++i) { kk[i] = (float4v){0,0,0,0}; qk[i] = (float4v){0,0,0,0}; }

    const unsigned short* aKp = K + (blk * 4 + w) * 16384 + (size_t)lane * 8;
    const unsigned short* aQp = Q + (blk * 4 + w) * 16384 + (size_t)lane * 8;
#pragma unroll 4
    for (int ks = 0; ks < 32; ++ks) {
        short8 aK = *(const short8*)(aKp + ks * 512);
        short8 aQ = *(const short8*)(aQp + ks * 512);
#pragma unroll
        for (int nb = 0; nb < 4; ++nb) {
            short8 bK = *(const short8*)(K + (blk * 4 + nb) * 16384 + (size_t)lane * 8 + ks * 512);
            kk[nb] = __builtin_amdgcn_mfma_f32_16x16x32_bf16(aK, bK, kk[nb], 0, 0, 0);
            qk[nb] = __builtin_amdgcn_mfma_f32_16x16x32_bf16(aQ, bK, qk[nb], 0, 0, 0);
        }
    }
#pragma unroll
    for (int nb = 0; nb < 4; ++nb)
#pragma unroll
        for (int r = 0; r < 4; ++r) {
            Skk[w * 16 + quad * 4 + r][nb * 16 + lm] = kk[nb][r];
            Sqk[w * 16 + quad * 4 + r][nb * 16 + lm] = qk[nb][r];
        }
    __syncthreads();

    const float c1 = 2.0f * LR / 1024.0f;
#pragma unroll
    for (int e = 0; e < 16; ++e) {
        int idx = tid * 16 + e;
        int t = idx >> 6, i = idx & 63;
        float a = (i < t) ? c1 * (Skk[t][i] + 1.0f) : 0.0f;
        Lb[t][i] = f2bf(a);
        Xa[i][t] = f2bf(((i == t) ? 1.0f : 0.0f) - a);
        float mq = (i <= t) ? -LR * (Sqk[t][i] + 1.0f) : 0.0f;
        MpG[blk * 4096 + (size_t)t * 64 + i] = f2bf(mq);
    }
    __syncthreads();

    short8 afL0 = *(const short8*)&Lb[w * 16 + lm][quad * 8];
    short8 afL1 = *(const short8*)&Lb[w * 16 + lm][32 + quad * 8];
    float4v p[4];
#pragma unroll
    for (int nb = 0; nb < 4; ++nb) {
        p[nb] = (float4v){0,0,0,0};
        short8 b0f = *(const short8*)&Xa[nb * 16 + lm][quad * 8];
        short8 b1f = *(const short8*)&Xa[nb * 16 + lm][32 + quad * 8];
        p[nb] = __builtin_amdgcn_mfma_f32_16x16x32_bf16(afL0, b0f, p[nb], 0, 0, 0);
        p[nb] = __builtin_amdgcn_mfma_f32_16x16x32_bf16(afL1, b1f, p[nb], 0, 0, 0);
    }
    __syncthreads();
#pragma unroll
    for (int nb = 0; nb < 4; ++nb)
#pragma unroll
        for (int r = 0; r < 4; ++r) {
            int ii = nb * 16 + lm, tt = w * 16 + quad * 4 + r;
            Xa[ii][tt] = f2bf(((ii == tt) ? 1.0f : 0.0f) - p[nb][r]);
        }
    __syncthreads();

#pragma unroll
    for (int nb = 0; nb < 4; ++nb) {
        p[nb] = (float4v){0,0,0,0};
        short8 b0f = *(const short8*)&Xa[nb * 16 + lm][quad * 8];
        short8 b1f = *(const short8*)&Xa[nb * 16 + lm][32 + quad * 8];
        p[nb] = __builtin_amdgcn_mfma_f32_16x16x32_bf16(afL0, b0f, p[nb], 0, 0, 0);
        p[nb] = __builtin_amdgcn_mfma_f32_16x16x32_bf16(afL1, b1f, p[nb], 0, 0, 0);
    }
#pragma unroll
    for (int nb = 0; nb < 4; ++nb)
#pragma unroll
        for (int r = 0; r < 4; ++r) {
            int ii = nb * 16 + lm, tt = w * 16 + quad * 4 + r;
            LinvG[blk * 4096 + (size_t)tt * 64 + ii] =
                f2bf(((ii == tt) ? 1.0f : 0.0f) - p[nb][r]);
        }
}

// ---------------------------------------------------------------------------
// Phase 3: role-split ttt (verified round 7/9) + BATCHED LOADS in (b)/(e):
// explicit groups of 8 independent global loads into NAMED short8 vars
// (within-phase lifetime, no barrier crossing, no arrays), then the MFMAs.
// Accumulation order per accumulator unchanged -> bit-identical results.
// ---------------------------------------------------------------------------
__global__ __launch_bounds__(512, 2) void ttt_chunk(
    const unsigned short* __restrict__ K,    // frag-major
    const unsigned short* __restrict__ V,    // row-major
    const unsigned short* __restrict__ Q,    // frag-major
    const unsigned short* __restrict__ Kt,
    const unsigned short* __restrict__ Linv,
    const unsigned short* __restrict__ Mp,
    const float* __restrict__ W0,
    const float* __restrict__ b0,
    float* __restrict__ out)
{
    __shared__ unsigned short Wb[32][1032];   // bf16 W mirror (66 KB)
    __shared__ unsigned short Ut[32][72];
    __shared__ unsigned short Gt[32][72];
    __shared__ __align__(16) float bb[32];

    const int tid  = threadIdx.x;
    const int lane = tid & 63;
    const int w    = tid >> 6;          // wave 0..7
    const int g    = w & 3;             // token-group
    const int role = w >> 2;            // 0 = U-producer (K), 1 = O-producer (Q)
    const int lm   = lane & 15;
    const int quad = lane >> 4;
    const int batch = blockIdx.x & 7;
    const int r0    = (blockIdx.x >> 3) * 32;   // row-slab base (32 rows)

    float4v acc_w[2][8];
#pragma unroll
    for (int rs2 = 0; rs2 < 2; ++rs2)
#pragma unroll
        for (int i = 0; i < 8; ++i) {
            int nt = w + 8 * i;
#pragma unroll
            for (int r = 0; r < 4; ++r)
                acc_w[rs2][i][r] =
                    W0[(size_t)(r0 + rs2 * 16 + quad * 4 + r) * 1024 + nt * 16 + lm];
        }
    if (tid < 32) bb[tid] = b0[r0 + tid];

    const size_t tokBase = (size_t)batch * 2048;
    const unsigned short* KtB = Kt + (size_t)batch * 2097152;
    const unsigned short* X = role ? Q : K;     // this wave's (b) operand stream
    const float sc = 2.0f / 1024.0f;

    for (int c = 0; c < 32; ++c) {
        // (a) dump fp32 W regs -> bf16 LDS mirror (both halves)
#pragma unroll
        for (int rs2 = 0; rs2 < 2; ++rs2)
#pragma unroll
            for (int i = 0; i < 8; ++i) {
                int nt = w + 8 * i;
#pragma unroll
                for (int r = 0; r < 4; ++r)
                    Wb[rs2 * 16 + quad * 4 + r][nt * 16 + lm] = f2bf(acc_w[rs2][i][r]);
            }
        __syncthreads();   // B1: Wb ready

        // (b) role-split contraction, BATCHED: per group, 8 independent X
        // loads issued up-front (8 in flight), then 16 MFMAs. Same ks order.
        const size_t tok = tokBase + c * 64 + g * 16 + lm;   // for V / out
        const unsigned short* xRow =
            X + (((size_t)batch * 32 + c) * 4 + g) * 16384 + (size_t)lane * 8;
        const unsigned short* wRow0 = &Wb[lm][quad * 8];
        const unsigned short* wRow1 = &Wb[16 + lm][quad * 8];
        float4v a0v = (float4v){0,0,0,0};
        float4v a1v = (float4v){0,0,0,0};
#pragma unroll
        for (int kb = 0; kb < 4; ++kb) {
            const unsigned short* xb = xRow + (size_t)(kb * 8) * 512;
            short8 x0 = *(const short8*)(xb);
            short8 x1 = *(const short8*)(xb + 512);
            short8 x2 = *(const short8*)(xb + 1024);
            short8 x3 = *(const short8*)(xb + 1536);
            short8 x4 = *(const short8*)(xb + 2048);
            short8 x5 = *(const short8*)(xb + 2560);
            short8 x6 = *(const short8*)(xb + 3072);
            short8 x7 = *(const short8*)(xb + 3584);
            const unsigned short* w0b = wRow0 + kb * 8 * 32;
            const unsigned short* w1b = wRow1 + kb * 8 * 32;
            a0v = __builtin_amdgcn_mfma_f32_16x16x32_bf16(*(const short8*)(w0b),       x0, a0v, 0, 0, 0);
            a1v = __builtin_amdgcn_mfma_f32_16x16x32_bf16(*(const short8*)(w1b),       x0, a1v, 0, 0, 0);
            a0v = __builtin_amdgcn_mfma_f32_16x16x32_bf16(*(const short8*)(w0b + 32),  x1, a0v, 0, 0, 0);
            a1v = __builtin_amdgcn_mfma_f32_16x16x32_bf16(*(const short8*)(w1b + 32),  x1, a1v, 0, 0, 0);
            a0v = __builtin_amdgcn_mfma_f32_16x16x32_bf16(*(const short8*)(w0b + 64),  x2, a0v, 0, 0, 0);
            a1v = __builtin_amdgcn_mfma_f32_16x16x32_bf16(*(const short8*)(w1b + 64),  x2, a1v, 0, 0, 0);
            a0v = __builtin_amdgcn_mfma_f32_16x16x32_bf16(*(const short8*)(w0b + 96),  x3, a0v, 0, 0, 0);
            a1v = __builtin_amdgcn_mfma_f32_16x16x32_bf16(*(const short8*)(w1b + 96),  x3, a1v, 0, 0, 0);
            a0v = __builtin_amdgcn_mfma_f32_16x16x32_bf16(*(const short8*)(w0b + 128), x4, a0v, 0, 0, 0);
            a1v = __builtin_amdgcn_mfma_f32_16x16x32_bf16(*(const short8*)(w1b + 128), x4, a1v, 0, 0, 0);
            a0v = __builtin_amdgcn_mfma_f32_16x16x32_bf16(*(const short8*)(w0b + 160), x5, a0v, 0, 0, 0);
            a1v = __builtin_amdgcn_mfma_f32_16x16x32_bf16(*(const short8*)(w1b + 160), x5, a1v, 0, 0, 0);
            a0v = __builtin_amdgcn_mfma_f32_16x16x32_bf16(*(const short8*)(w0b + 192), x6, a0v, 0, 0, 0);
            a1v = __builtin_amdgcn_mfma_f32_16x16x32_bf16(*(const short8*)(w1b + 192), x6, a1v, 0, 0, 0);
            a0v = __builtin_amdgcn_mfma_f32_16x16x32_bf16(*(const short8*)(w0b + 224), x7, a0v, 0, 0, 0);
            a1v = __builtin_amdgcn_mfma_f32_16x16x32_bf16(*(const short8*)(w1b + 224), x7, a1v, 0, 0, 0);
        }
        float4v bval0 = *(const float4v*)&bb[quad * 4];
        float4v bval1 = *(const float4v*)&bb[16 + quad * 4];
        if (role == 0) {
            ushort4v vv0 = *(const ushort4v*)(V + tok * 1024 + r0 + quad * 4);
            ushort4v vv1 = *(const ushort4v*)(V + tok * 1024 + r0 + 16 + quad * 4);
#pragma unroll
            for (int r = 0; r < 4; ++r) {
                Ut[quad * 4 + r][g * 16 + lm]      = f2bf(sc * (a0v[r] + bval0[r] - bf2f(vv0[r])));
                Ut[16 + quad * 4 + r][g * 16 + lm] = f2bf(sc * (a1v[r] + bval1[r] - bf2f(vv1[r])));
            }
        }
        __syncthreads();   // B2: Ut ready

        const size_t lbase = ((size_t)(batch * 32 + c)) * 4096 + (size_t)(g * 16 + lm) * 64;

        // (c) G^T: wave (g,role) handles row-half = role
        {
            float4v accG = (float4v){0,0,0,0};
            short8 a0 = *(const short8*)&Ut[role * 16 + lm][quad * 8];
            short8 a1 = *(const short8*)&Ut[role * 16 + lm][32 + quad * 8];
            short8 l0 = *(const short8*)(Linv + lbase + quad * 8);
            short8 l1 = *(const short8*)(Linv + lbase + 32 + quad * 8);
            accG = __builtin_amdgcn_mfma_f32_16x16x32_bf16(a0, l0, accG, 0, 0, 0);
            accG = __builtin_amdgcn_mfma_f32_16x16x32_bf16(a1, l1, accG, 0, 0, 0);
#pragma unroll
            for (int r = 0; r < 4; ++r)
                Gt[role * 16 + quad * 4 + r][g * 16 + lm] = f2bf(accG[r]);
        }
        __syncthreads();   // B3: Gt ready

        short8 agA0 = *(const short8*)&Gt[lm][quad * 8];
        short8 agA1 = *(const short8*)&Gt[lm][32 + quad * 8];
        short8 agB0 = *(const short8*)&Gt[16 + lm][quad * 8];
        short8 agB1 = *(const short8*)&Gt[16 + lm][32 + quad * 8];

        // (d) role-1 waves: O += Gt . Mp + b ; store both row halves
        if (role == 1) {
            short8 m0f = *(const short8*)(Mp + lbase + quad * 8);
            short8 m1f = *(const short8*)(Mp + lbase + 32 + quad * 8);
            a0v = __builtin_amdgcn_mfma_f32_16x16x32_bf16(agA0, m0f, a0v, 0, 0, 0);
            a0v = __builtin_amdgcn_mfma_f32_16x16x32_bf16(agA1, m1f, a0v, 0, 0, 0);
            a1v = __builtin_amdgcn_mfma_f32_16x16x32_bf16(agB0, m0f, a1v, 0, 0, 0);
            a1v = __builtin_amdgcn_mfma_f32_16x16x32_bf16(agB1, m1f, a1v, 0, 0, 0);
            float4v ov0, ov1;
#pragma unroll
            for (int r = 0; r < 4; ++r) { ov0[r] = a0v[r] + bval0[r]; ov1[r] = a1v[r] + bval1[r]; }
            *(float4v*)(out + tok * 1024 + r0 + quad * 4)      = ov0;
            *(float4v*)(out + tok * 1024 + r0 + 16 + quad * 4) = ov1;
        }

        // (e) W += Gt . Kt-contraction, BATCHED: per group, 8 independent Kt
        // loads (4 tiles x 2) into named vars, then 16 MFMAs. Same per-acc order.
#pragma unroll
        for (int ib = 0; ib < 2; ++ib) {
            const int i0 = ib * 4;
            const unsigned short* kp0 = KtB + (size_t)((w + 8 * (i0 + 0)) * 16 + lm) * 2048 + c * 64 + quad * 8;
            const unsigned short* kp1 = KtB + (size_t)((w + 8 * (i0 + 1)) * 16 + lm) * 2048 + c * 64 + quad * 8;
            const unsigned short* kp2 = KtB + (size_t)((w + 8 * (i0 + 2)) * 16 + lm) * 2048 + c * 64 + quad * 8;
            const unsigned short* kp3 = KtB + (size_t)((w + 8 * (i0 + 3)) * 16 + lm) * 2048 + c * 64 + quad * 8;
            short8 kA0 = *(const short8*)(kp0);
            short8 kA1 = *(const short8*)(kp0 + 32);
            short8 kB0 = *(const short8*)(kp1);
            short8 kB1 = *(const short8*)(kp1 + 32);
            short8 kC0 = *(const short8*)(kp2);
            short8 kC1 = *(const short8*)(kp2 + 32);
            short8 kD0 = *(const short8*)(kp3);
            short8 kD1 = *(const short8*)(kp3 + 32);
            acc_w[0][i0 + 0] = __builtin_amdgcn_mfma_f32_16x16x32_bf16(agA0, kA0, acc_w[0][i0 + 0], 0, 0, 0);
            acc_w[0][i0 + 0] = __builtin_amdgcn_mfma_f32_16x16x32_bf16(agA1, kA1, acc_w[0][i0 + 0], 0, 0, 0);
            acc_w[1][i0 + 0] = __builtin_amdgcn_mfma_f32_16x16x32_bf16(agB0, kA0, acc_w[1][i0 + 0], 0, 0, 0);
            acc_w[1][i0 + 0] = __builtin_amdgcn_mfma_f32_16x16x32_bf16(agB1, kA1, acc_w[1][i0 + 0], 0, 0, 0);
            acc_w[0][i0 + 1] = __builtin_amdgcn_mfma_f32_16x16x32_bf16(agA0, kB0, acc_w[0][i0 + 1], 0, 0, 0);
            acc_w[0][i0 + 1] = __builtin_amdgcn_mfma_f32_16x16x32_bf16(agA1, kB1, acc_w[0][i0 + 1], 0, 0, 0);
            acc_w[1][i0 + 1] = __builtin_amdgcn_mfma_f32_16x16x32_bf16(agB0, kB0, acc_w[1][i0 + 1], 0, 0, 0);
            acc_w[1][i0 + 1] = __builtin_amdgcn_mfma_f32_16x16x32_bf16(agB1, kB1, acc_w[1][i0 + 1], 0, 0, 0);
            acc_w[0][i0 + 2] = __builtin_amdgcn_mfma_f32_16x16x32_bf16(agA0, kC0, acc_w[0][i0 + 2], 0, 0, 0);
            acc_w[0][i0 + 2] = __builtin_amdgcn_mfma_f32_16x16x32_bf16(agA1, kC1, acc_w[0][i0 + 2], 0, 0, 0);
            acc_w[1][i0 + 2] = __builtin_amdgcn_mfma_f32_16x16x32_bf16(agB0, kC0, acc_w[1][i0 + 2], 0, 0, 0);
            acc_w[1][i0 + 2] = __builtin_amdgcn_mfma_f32_16x16x32_bf16(agB1, kC1, acc_w[1][i0 + 2], 0, 0, 0);
            acc_w[0][i0 + 3] = __builtin_amdgcn_mfma_f32_16x16x32_bf16(agA0, kD0, acc_w[0][i0 + 3], 0, 0, 0);
            acc_w[0][i0 + 3] = __builtin_amdgcn_mfma_f32_16x16x32_bf16(agA1, kD1, acc_w[0][i0 + 3], 0, 0, 0);
            acc_w[1][i0 + 3] = __builtin_amdgcn_mfma_f32_16x16x32_bf16(agB0, kD0, acc_w[1][i0 + 3], 0, 0, 0);
            acc_w[1][i0 + 3] = __builtin_amdgcn_mfma_f32_16x16x32_bf16(agB1, kD1, acc_w[1][i0 + 3], 0, 0, 0);
        }

        // (f) bias update: wave 0, 2 lanes per row + shuffle reduce
        if (w == 0) {
            int row = lane >> 1, part = lane & 1;
            float s = 0.f;
#pragma unroll
            for (int t = 0; t < 32; ++t) s += bf2f(Gt[row][part * 32 + t]);
            s += __shfl_xor(s, 1);
            if (part == 0) bb[row] -= LR * s;
        }
        __syncthreads();   // B4: end-of-chunk
    }
}

// ---------------------------------------------------------------------------
extern "C" void kernel_launch(void* const* d_in, const int* in_sizes, int n_in,
                              void* d_out, int out_size, void* d_ws, size_t ws_size,
                              hipStream_t stream) {
    (void)in_sizes; (void)n_in; (void)out_size;
    const float* in_seq = (const float*)d_in[0];
    const float* thK    = (const float*)d_in[1];
    const float* thV    = (const float*)d_in[2];
    const float* thQ    = (const float*)d_in[3];
    const float* W0     = (const float*)d_in[4];
    const float* b0     = (const float*)d_in[5];
    float* out = (float*)d_out;

    unsigned short* ws = (unsigned short*)d_ws;
    unsigned short* Kf   = ws;                                  // 32 MB (frag-major)
    unsigned short* Vp   = ws + (size_t)16384 * 1024;           // 32 MB (row-major)
    unsigned short* Qf   = ws + (size_t)2 * 16384 * 1024;       // 32 MB (frag-major)
    unsigned short* Ktp  = ws + (size_t)3 * 16384 * 1024;       // 32 MB
    unsigned short* Linv = ws + (size_t)4 * 16384 * 1024;       // 2 MB
    unsigned short* Mpp  = Linv + (size_t)8 * 32 * 4096;        // 2 MB
    unsigned short* Abf  = Mpp + (size_t)8 * 32 * 4096;         // 32 MB (pre-cast A)
    unsigned short* Tbf  = Abf + (size_t)16384 * 1024;          // 6 MB  (pre-cast thetas)

    const size_t need_shorts = (size_t)4 * 16384 * 1024 + 2 * (size_t)8 * 32 * 4096
                             + (size_t)16384 * 1024 + (size_t)3 * 1024 * 1024;

    dim3 g1(16384 / 64, 1024 / 64);
    if (ws_size >= need_shorts * 2) {
        cast_all<<<2432, 256, 0, stream>>>(in_seq, thK, thV, thQ, Abf, Tbf);
        proj_gemm_bf<<<g1, 256, 0, stream>>>(Abf, Tbf, Kf, Vp, Qf, Ktp);
    } else {
        proj_gemm<<<g1, 256, 0, stream>>>(in_seq, thK, thV, thQ, Kf, Vp, Qf, Ktp);
    }

    precomp<<<256, 256, 0, stream>>>(Kf, Qf, Linv, Mpp);

    ttt_chunk<<<256, 512, 0, stream>>>(Kf, Vp, Qf, Ktp, Linv, Mpp, W0, b0, out);
}

// Round 11
// 626.433 us; speedup vs baseline: 1.2775x; 1.0648x over previous
//
#include <hip/hip_runtime.h>
#include <hip/hip_bf16.h>

#define LR 0.01f

typedef __attribute__((ext_vector_type(8))) short short8;
typedef __attribute__((ext_vector_type(4))) float float4v;
typedef __attribute__((ext_vector_type(4))) unsigned short ushort4v;

static __device__ __forceinline__ unsigned short f2bf(float x) {
    union { float f; unsigned u; } un; un.f = x;
    unsigned r = un.u + 0x7fffu + ((un.u >> 16) & 1u);   // RNE
    return (unsigned short)(r >> 16);
}
static __device__ __forceinline__ float bf2f(unsigned short x) {
    union { float f; unsigned u; } un; un.u = ((unsigned)x) << 16;
    return un.f;
}

// Fragment-major index for K/Q (verified round 9): element K[b][s][j] at
// ((((b*32+c)*4+tt)*32+ks)*512) + (qd*16+lm)*8 + e  with c=s>>6, tt=(s>>4)&3,
// lm=s&15, ks=j>>5, qd=(j>>3)&3, e=j&7.
static __device__ __forceinline__ size_t kq_frag_idx(int b, int s, int j) {
    return ((((size_t)(b * 32 + (s >> 6)) * 4 + ((s >> 4) & 3)) * 32 + (j >> 5)) * 512)
         + (size_t)(((j >> 3) & 3) * 16 + (s & 15)) * 8 + (j & 7);
}

// ---------------------------------------------------------------------------
// Phase 0: one-shot fp32 -> bf16 cast of A and thetas (verified round 8).
// ---------------------------------------------------------------------------
__global__ __launch_bounds__(256) void cast_all(
    const float* __restrict__ A,
    const float* __restrict__ T0, const float* __restrict__ T1,
    const float* __restrict__ T2,
    unsigned short* __restrict__ Ab,
    unsigned short* __restrict__ Tb)
{
    const int bid = blockIdx.x;
    const int tid = threadIdx.x;
    if (bid < 2048) {
        for (int i = bid * 256 + tid; i < 2097152; i += 2048 * 256) {
            const float4v* s = (const float4v*)(A + (size_t)i * 8);
            float4v a = s[0], b = s[1];
            short8 o;
#pragma unroll
            for (int j = 0; j < 4; ++j) { o[j] = (short)f2bf(a[j]); o[j + 4] = (short)f2bf(b[j]); }
            *(short8*)(Ab + (size_t)i * 8) = o;
        }
    } else {
        const int base = bid - 2048;
        const int t = base >> 7;
        const int lb = base & 127;
        const float* S = (t == 0) ? T0 : (t == 1 ? T1 : T2);
        unsigned short* D = Tb + (size_t)t * 1048576;
        for (int i = lb * 256 + tid; i < 131072; i += 128 * 256) {
            const float4v* s = (const float4v*)(S + (size_t)i * 8);
            float4v a = s[0], b = s[1];
            short8 o;
#pragma unroll
            for (int j = 0; j < 4; ++j) { o[j] = (short)f2bf(a[j]); o[j + 4] = (short)f2bf(b[j]); }
            *(short8*)(D + (size_t)i * 8) = o;
        }
    }
}

// ---------------------------------------------------------------------------
// Phase 1 (fast path, NEW): 128x128-tile z-merged projection from pre-cast
// bf16 (m93-shape: 512 thr, 8 waves = 2M x 4N, 24 MFMA per 10 ds_read_b128
// per wave per k-step). Same kt-ascending MFMA chains as the verified 64^2
// proj -> bit-identical outputs. Stores: frag-major K/Q, row-major V, Kt.
// ---------------------------------------------------------------------------
__global__ __launch_bounds__(512) void proj128_bf(
    const unsigned short* __restrict__ A,    // bf16 [16384][1024]
    const unsigned short* __restrict__ Tb,   // bf16 [3][1024][1024]
    unsigned short* __restrict__ Kf,
    unsigned short* __restrict__ Vp,
    unsigned short* __restrict__ Qf,
    unsigned short* __restrict__ ktw)
{
    __shared__ unsigned short As[128][40];
    __shared__ unsigned short Bs[3][128][40];

    const int tid  = threadIdx.x;
    const int lane = tid & 63;
    const int w    = tid >> 6;         // 0..7
    const int lm   = lane & 15;
    const int quad = lane >> 4;
    const int wr   = w & 1;            // m-half (0..1) -> 64-row block
    const int wc   = w >> 1;           // n-quarter (0..3) -> 32-col block
    const int m0   = blockIdx.x * 128;
    const int n0   = blockIdx.y * 128;

    const int srow = tid >> 2;         // 0..127 staging row
    const int sseg = (tid & 3) * 8;    // 0,8,16,24

    float4v acc[3][4][2];
#pragma unroll
    for (int z = 0; z < 3; ++z)
#pragma unroll
        for (int mi = 0; mi < 4; ++mi)
#pragma unroll
            for (int ni = 0; ni < 2; ++ni) acc[z][mi][ni] = (float4v){0.f, 0.f, 0.f, 0.f};

    const unsigned short* apS  = A                 + (size_t)(m0 + srow) * 1024 + sseg;
    const unsigned short* bpS0 = Tb                + (size_t)(n0 + srow) * 1024 + sseg;
    const unsigned short* bpS1 = Tb + 1048576      + (size_t)(n0 + srow) * 1024 + sseg;
    const unsigned short* bpS2 = Tb + 2 * 1048576  + (size_t)(n0 + srow) * 1024 + sseg;

    for (int kt = 0; kt < 1024; kt += 32) {
        short8 av = *(const short8*)(apS + kt);
        short8 b0 = *(const short8*)(bpS0 + kt);
        short8 b1 = *(const short8*)(bpS1 + kt);
        short8 b2 = *(const short8*)(bpS2 + kt);

        __syncthreads();
        *(short8*)&As[srow][sseg]    = av;
        *(short8*)&Bs[0][srow][sseg] = b0;
        *(short8*)&Bs[1][srow][sseg] = b1;
        *(short8*)&Bs[2][srow][sseg] = b2;
        __syncthreads();

        short8 af0 = *(const short8*)&As[wr * 64 +  0 + lm][quad * 8];
        short8 af1 = *(const short8*)&As[wr * 64 + 16 + lm][quad * 8];
        short8 af2 = *(const short8*)&As[wr * 64 + 32 + lm][quad * 8];
        short8 af3 = *(const short8*)&As[wr * 64 + 48 + lm][quad * 8];
#pragma unroll
        for (int z = 0; z < 3; ++z) {
#pragma unroll
            for (int ni = 0; ni < 2; ++ni) {
                short8 bfr = *(const short8*)&Bs[z][wc * 32 + ni * 16 + lm][quad * 8];
                acc[z][0][ni] = __builtin_amdgcn_mfma_f32_16x16x32_bf16(af0, bfr, acc[z][0][ni], 0, 0, 0);
                acc[z][1][ni] = __builtin_amdgcn_mfma_f32_16x16x32_bf16(af1, bfr, acc[z][1][ni], 0, 0, 0);
                acc[z][2][ni] = __builtin_amdgcn_mfma_f32_16x16x32_bf16(af2, bfr, acc[z][2][ni], 0, 0, 0);
                acc[z][3][ni] = __builtin_amdgcn_mfma_f32_16x16x32_bf16(af3, bfr, acc[z][3][ni], 0, 0, 0);
            }
        }
    }

    const int batch = m0 >> 11;        // 128 | 2048 -> tile never spans batches
    const int s0    = m0 & 2047;
#pragma unroll
    for (int mi = 0; mi < 4; ++mi) {
#pragma unroll
        for (int ni = 0; ni < 2; ++ni) {
#pragma unroll
            for (int r = 0; r < 4; ++r) {
                int tl = wr * 64 + mi * 16 + quad * 4 + r;   // token-local
                int jl = wc * 32 + ni * 16 + lm;             // dim-local
                int s = s0 + tl;
                int j = n0 + jl;
                size_t fK = kq_frag_idx(batch, s, j);
                Kf[fK] = f2bf(acc[0][mi][ni][r]);
                Qf[fK] = f2bf(acc[2][mi][ni][r]);
                Vp[(size_t)(m0 + tl) * 1024 + j] = f2bf(acc[1][mi][ni][r]);
                ktw[(size_t)batch * 2097152 + (size_t)j * 2048 + s] =
                    f2bf(-LR * acc[0][mi][ni][r]);
            }
        }
    }
}

// ---------------------------------------------------------------------------
// Phase 1 (fallback, verified): fp32-input 64^2 proj, frag-major stores.
// ---------------------------------------------------------------------------
__global__ __launch_bounds__(256) void proj_gemm(
    const float* __restrict__ A,
    const float* __restrict__ T0, const float* __restrict__ T1,
    const float* __restrict__ T2,
    unsigned short* __restrict__ Kf,
    unsigned short* __restrict__ Vp,
    unsigned short* __restrict__ Qf,
    unsigned short* __restrict__ ktw)
{
    __shared__ unsigned short As[64][40];
    __shared__ unsigned short Bs[3][64][40];

    const int tid  = threadIdx.x;
    const int lane = tid & 63;
    const int wave = tid >> 6;
    const int m0 = blockIdx.x * 64;
    const int n0 = blockIdx.y * 64;
    const int srow = tid >> 2;
    const int sseg = (tid & 3) * 8;
    const int mrow = lane & 15;
    const int quad = lane >> 4;

    float4v acc[3][4];
#pragma unroll
    for (int z = 0; z < 3; ++z)
#pragma unroll
        for (int i = 0; i < 4; ++i) acc[z][i] = (float4v){0.f, 0.f, 0.f, 0.f};

    const float* apBase = A  + (size_t)(m0 + srow) * 1024 + sseg;
    const float* bp0 = T0 + (size_t)(n0 + srow) * 1024 + sseg;
    const float* bp1 = T1 + (size_t)(n0 + srow) * 1024 + sseg;
    const float* bp2 = T2 + (size_t)(n0 + srow) * 1024 + sseg;

    for (int kt = 0; kt < 1024; kt += 32) {
        float4v av0 = ((const float4v*)(apBase + kt))[0];
        float4v av1 = ((const float4v*)(apBase + kt))[1];
        float4v b00 = ((const float4v*)(bp0 + kt))[0], b01 = ((const float4v*)(bp0 + kt))[1];
        float4v b10 = ((const float4v*)(bp1 + kt))[0], b11 = ((const float4v*)(bp1 + kt))[1];
        float4v b20 = ((const float4v*)(bp2 + kt))[0], b21 = ((const float4v*)(bp2 + kt))[1];

        __syncthreads();
        short8 apk, bpk0, bpk1, bpk2;
#pragma unroll
        for (int i = 0; i < 4; ++i) {
            apk[i]      = (short)f2bf(av0[i]);
            apk[i + 4]  = (short)f2bf(av1[i]);
            bpk0[i]     = (short)f2bf(b00[i]);
            bpk0[i + 4] = (short)f2bf(b01[i]);
            bpk1[i]     = (short)f2bf(b10[i]);
            bpk1[i + 4] = (short)f2bf(b11[i]);
            bpk2[i]     = (short)f2bf(b20[i]);
            bpk2[i + 4] = (short)f2bf(b21[i]);
        }
        *(short8*)&As[srow][sseg]    = apk;
        *(short8*)&Bs[0][srow][sseg] = bpk0;
        *(short8*)&Bs[1][srow][sseg] = bpk1;
        *(short8*)&Bs[2][srow][sseg] = bpk2;
        __syncthreads();

        short8 af = *(const short8*)&As[16 * wave + mrow][quad * 8];
#pragma unroll
        for (int z = 0; z < 3; ++z)
#pragma unroll
            for (int nb = 0; nb < 4; ++nb) {
                short8 bfr = *(const short8*)&Bs[z][16 * nb + mrow][quad * 8];
                acc[z][nb] = __builtin_amdgcn_mfma_f32_16x16x32_bf16(af, bfr, acc[z][nb], 0, 0, 0);
            }
    }

    const int batch = m0 >> 11;
    const int s0    = m0 & 2047;
#pragma unroll
    for (int nb = 0; nb < 4; ++nb) {
#pragma unroll
        for (int r = 0; r < 4; ++r) {
            int tl = 16 * wave + quad * 4 + r;
            int jl = 16 * nb + mrow;
            int s = s0 + tl;
            int j = n0 + jl;
            size_t fK = kq_frag_idx(batch, s, j);
            Kf[fK] = f2bf(acc[0][nb][r]);
            Qf[fK] = f2bf(acc[2][nb][r]);
            Vp[(size_t)(m0 + tl) * 1024 + j] = f2bf(acc[1][nb][r]);
            ktw[(size_t)batch * 2097152 + (size_t)j * 2048 + s] = f2bf(-LR * acc[0][nb][r]);
        }
    }
}

// ---------------------------------------------------------------------------
// Phase 2: Linv/Mp precompute from frag-major K/Q (verified round 9).
// ---------------------------------------------------------------------------
__global__ __launch_bounds__(256) void precomp(
    const unsigned short* __restrict__ K,    // frag-major
    const unsigned short* __restrict__ Q,    // frag-major
    unsigned short* __restrict__ LinvG,
    unsigned short* __restrict__ MpG)
{
    __shared__ float Skk[64][68];
    __shared__ float Sqk[64][68];
    __shared__ unsigned short Lb[64][72];
    __shared__ unsigned short Xa[64][72];

    const int tid = threadIdx.x;
    const int lane = tid & 63;
    const int w = tid >> 6;
    const int lm = lane & 15;
    const int quad = lane >> 4;
    const int batch = blockIdx.x >> 5;
    const int c = blockIdx.x & 31;
    const size_t blk = (size_t)batch * 32 + c;

    float4v kk[4], qk[4];
#pragma unroll
    for (int i = 0; i < 4; ++i) { kk[i] = (float4v){0,0,0,0}; qk[i] = (float4v){0,0,0,0}; }

    const unsigned short* aKp = K + (blk * 4 + w) * 16384 + (size_t)lane * 8;
    const unsigned short* aQp = Q + (blk * 4 + w) * 16384 + (size_t)lane * 8;
#pragma unroll 4
    for (int ks = 0; ks < 32; ++ks) {
        short8 aK = *(const short8*)(aKp + ks * 512);
        short8 aQ = *(const short8*)(aQp + ks * 512);
#pragma unroll
        for (int nb = 0; nb < 4; ++nb) {
            short8 bK = *(const short8*)(K + (blk * 4 + nb) * 16384 + (size_t)lane * 8 + ks * 512);
            kk[nb] = __builtin_amdgcn_mfma_f32_16x16x32_bf16(aK, bK, kk[nb], 0, 0, 0);
            qk[nb] = __builtin_amdgcn_mfma_f32_16x16x32_bf16(aQ, bK, qk[nb], 0, 0, 0);
        }
    }
#pragma unroll
    for (int nb = 0; nb < 4; ++nb)
#pragma unroll
        for (int r = 0; r < 4; ++r) {
            Skk[w * 16 + quad * 4 + r][nb * 16 + lm] = kk[nb][r];
            Sqk[w * 16 + quad * 4 + r][nb * 16 + lm] = qk[nb][r];
        }
    __syncthreads();

    const float c1 = 2.0f * LR / 1024.0f;
#pragma unroll
    for (int e = 0; e < 16; ++e) {
        int idx = tid * 16 + e;
        int t = idx >> 6, i = idx & 63;
        float a = (i < t) ? c1 * (Skk[t][i] + 1.0f) : 0.0f;
        Lb[t][i] = f2bf(a);
        Xa[i][t] = f2bf(((i == t) ? 1.0f : 0.0f) - a);
        float mq = (i <= t) ? -LR * (Sqk[t][i] + 1.0f) : 0.0f;
        MpG[blk * 4096 + (size_t)t * 64 + i] = f2bf(mq);
    }
    __syncthreads();

    short8 afL0 = *(const short8*)&Lb[w * 16 + lm][quad * 8];
    short8 afL1 = *(const short8*)&Lb[w * 16 + lm][32 + quad * 8];
    float4v p[4];
#pragma unroll
    for (int nb = 0; nb < 4; ++nb) {
        p[nb] = (float4v){0,0,0,0};
        short8 b0f = *(const short8*)&Xa[nb * 16 + lm][quad * 8];
        short8 b1f = *(const short8*)&Xa[nb * 16 + lm][32 + quad * 8];
        p[nb] = __builtin_amdgcn_mfma_f32_16x16x32_bf16(afL0, b0f, p[nb], 0, 0, 0);
        p[nb] = __builtin_amdgcn_mfma_f32_16x16x32_bf16(afL1, b1f, p[nb], 0, 0, 0);
    }
    __syncthreads();
#pragma unroll
    for (int nb = 0; nb < 4; ++nb)
#pragma unroll
        for (int r = 0; r < 4; ++r) {
            int ii = nb * 16 + lm, tt = w * 16 + quad * 4 + r;
            Xa[ii][tt] = f2bf(((ii == tt) ? 1.0f : 0.0f) - p[nb][r]);
        }
    __syncthreads();

#pragma unroll
    for (int nb = 0; nb < 4; ++nb) {
        p[nb] = (float4v){0,0,0,0};
        short8 b0f = *(const short8*)&Xa[nb * 16 + lm][quad * 8];
        short8 b1f = *(const short8*)&Xa[nb * 16 + lm][32 + quad * 8];
        p[nb] = __builtin_amdgcn_mfma_f32_16x16x32_bf16(afL0, b0f, p[nb], 0, 0, 0);
        p[nb] = __builtin_amdgcn_mfma_f32_16x16x32_bf16(afL1, b1f, p[nb], 0, 0, 0);
    }
#pragma unroll
    for (int nb = 0; nb < 4; ++nb)
#pragma unroll
        for (int r = 0; r < 4; ++r) {
            int ii = nb * 16 + lm, tt = w * 16 + quad * 4 + r;
            LinvG[blk * 4096 + (size_t)tt * 64 + ii] =
                f2bf(((ii == tt) ? 1.0f : 0.0f) - p[nb][r]);
        }
}

// ---------------------------------------------------------------------------
// Phase 3: role-split ttt (verified r7/r9/r10) with DEEPER in-phase batching:
// (b) 2 groups of 16 loads; (e) 1 group of 16; V issued at top of B1->B2
// interval (within-phase, not cross-barrier). Accumulation order unchanged.
// ---------------------------------------------------------------------------
__global__ __launch_bounds__(512, 2) void ttt_chunk(
    const unsigned short* __restrict__ K,    // frag-major
    const unsigned short* __restrict__ V,    // row-major
    const unsigned short* __restrict__ Q,    // frag-major
    const unsigned short* __restrict__ Kt,
    const unsigned short* __restrict__ Linv,
    const unsigned short* __restrict__ Mp,
    const float* __restrict__ W0,
    const float* __restrict__ b0,
    float* __restrict__ out)
{
    __shared__ unsigned short Wb[32][1032];   // bf16 W mirror (66 KB)
    __shared__ unsigned short Ut[32][72];
    __shared__ unsigned short Gt[32][72];
    __shared__ __align__(16) float bb[32];

    const int tid  = threadIdx.x;
    const int lane = tid & 63;
    const int w    = tid >> 6;          // wave 0..7
    const int g    = w & 3;             // token-group
    const int role = w >> 2;            // 0 = U-producer (K), 1 = O-producer (Q)
    const int lm   = lane & 15;
    const int quad = lane >> 4;
    const int batch = blockIdx.x & 7;
    const int r0    = (blockIdx.x >> 3) * 32;   // row-slab base (32 rows)

    float4v acc_w[2][8];
#pragma unroll
    for (int rs2 = 0; rs2 < 2; ++rs2)
#pragma unroll
        for (int i = 0; i < 8; ++i) {
            int nt = w + 8 * i;
#pragma unroll
            for (int r = 0; r < 4; ++r)
                acc_w[rs2][i][r] =
                    W0[(size_t)(r0 + rs2 * 16 + quad * 4 + r) * 1024 + nt * 16 + lm];
        }
    if (tid < 32) bb[tid] = b0[r0 + tid];

    const size_t tokBase = (size_t)batch * 2048;
    const unsigned short* KtB = Kt + (size_t)batch * 2097152;
    const unsigned short* X = role ? Q : K;     // this wave's (b) operand stream
    const float sc = 2.0f / 1024.0f;

    for (int c = 0; c < 32; ++c) {
        // (a) dump fp32 W regs -> bf16 LDS mirror (both halves)
#pragma unroll
        for (int rs2 = 0; rs2 < 2; ++rs2)
#pragma unroll
            for (int i = 0; i < 8; ++i) {
                int nt = w + 8 * i;
#pragma unroll
                for (int r = 0; r < 4; ++r)
                    Wb[rs2 * 16 + quad * 4 + r][nt * 16 + lm] = f2bf(acc_w[rs2][i][r]);
            }
        __syncthreads();   // B1: Wb ready

        // (b) role-split contraction; V issued first so its latency hides
        // under the 64 MFMAs (consumed before B2 -> same barrier interval).
        const size_t tok = tokBase + c * 64 + g * 16 + lm;   // for V / out
        ushort4v vv0 = *(const ushort4v*)(V + tok * 1024 + r0 + quad * 4);
        ushort4v vv1 = *(const ushort4v*)(V + tok * 1024 + r0 + 16 + quad * 4);
        const unsigned short* xRow =
            X + (((size_t)batch * 32 + c) * 4 + g) * 16384 + (size_t)lane * 8;
        const unsigned short* wRow0 = &Wb[lm][quad * 8];
        const unsigned short* wRow1 = &Wb[16 + lm][quad * 8];
        float4v a0v = (float4v){0,0,0,0};
        float4v a1v = (float4v){0,0,0,0};
#pragma unroll
        for (int kb = 0; kb < 2; ++kb) {
            const unsigned short* xb = xRow + (size_t)(kb * 16) * 512;
            short8 y0  = *(const short8*)(xb);
            short8 y1  = *(const short8*)(xb + 512);
            short8 y2  = *(const short8*)(xb + 1024);
            short8 y3  = *(const short8*)(xb + 1536);
            short8 y4  = *(const short8*)(xb + 2048);
            short8 y5  = *(const short8*)(xb + 2560);
            short8 y6  = *(const short8*)(xb + 3072);
            short8 y7  = *(const short8*)(xb + 3584);
            short8 y8  = *(const short8*)(xb + 4096);
            short8 y9  = *(const short8*)(xb + 4608);
            short8 y10 = *(const short8*)(xb + 5120);
            short8 y11 = *(const short8*)(xb + 5632);
            short8 y12 = *(const short8*)(xb + 6144);
            short8 y13 = *(const short8*)(xb + 6656);
            short8 y14 = *(const short8*)(xb + 7168);
            short8 y15 = *(const short8*)(xb + 7680);
            const unsigned short* w0b = wRow0 + kb * 16 * 32;
            const unsigned short* w1b = wRow1 + kb * 16 * 32;
            a0v = __builtin_amdgcn_mfma_f32_16x16x32_bf16(*(const short8*)(w0b),        y0,  a0v, 0, 0, 0);
            a1v = __builtin_amdgcn_mfma_f32_16x16x32_bf16(*(const short8*)(w1b),        y0,  a1v, 0, 0, 0);
            a0v = __builtin_amdgcn_mfma_f32_16x16x32_bf16(*(const short8*)(w0b + 32),   y1,  a0v, 0, 0, 0);
            a1v = __builtin_amdgcn_mfma_f32_16x16x32_bf16(*(const short8*)(w1b + 32),   y1,  a1v, 0, 0, 0);
            a0v = __builtin_amdgcn_mfma_f32_16x16x32_bf16(*(const short8*)(w0b + 64),   y2,  a0v, 0, 0, 0);
            a1v = __builtin_amdgcn_mfma_f32_16x16x32_bf16(*(const short8*)(w1b + 64),   y2,  a1v, 0, 0, 0);
            a0v = __builtin_amdgcn_mfma_f32_16x16x32_bf16(*(const short8*)(w0b + 96),   y3,  a0v, 0, 0, 0);
            a1v = __builtin_amdgcn_mfma_f32_16x16x32_bf16(*(const short8*)(w1b + 96),   y3,  a1v, 0, 0, 0);
            a0v = __builtin_amdgcn_mfma_f32_16x16x32_bf16(*(const short8*)(w0b + 128),  y4,  a0v, 0, 0, 0);
            a1v = __builtin_amdgcn_mfma_f32_16x16x32_bf16(*(const short8*)(w1b + 128),  y4,  a1v, 0, 0, 0);
            a0v = __builtin_amdgcn_mfma_f32_16x16x32_bf16(*(const short8*)(w0b + 160),  y5,  a0v, 0, 0, 0);
            a1v = __builtin_amdgcn_mfma_f32_16x16x32_bf16(*(const short8*)(w1b + 160),  y5,  a1v, 0, 0, 0);
            a0v = __builtin_amdgcn_mfma_f32_16x16x32_bf16(*(const short8*)(w0b + 192),  y6,  a0v, 0, 0, 0);
            a1v = __builtin_amdgcn_mfma_f32_16x16x32_bf16(*(const short8*)(w1b + 192),  y6,  a1v, 0, 0, 0);
            a0v = __builtin_amdgcn_mfma_f32_16x16x32_bf16(*(const short8*)(w0b + 224),  y7,  a0v, 0, 0, 0);
            a1v = __builtin_amdgcn_mfma_f32_16x16x32_bf16(*(const short8*)(w1b + 224),  y7,  a1v, 0, 0, 0);
            a0v = __builtin_amdgcn_mfma_f32_16x16x32_bf16(*(const short8*)(w0b + 256),  y8,  a0v, 0, 0, 0);
            a1v = __builtin_amdgcn_mfma_f32_16x16x32_bf16(*(const short8*)(w1b + 256),  y8,  a1v, 0, 0, 0);
            a0v = __builtin_amdgcn_mfma_f32_16x16x32_bf16(*(const short8*)(w0b + 288),  y9,  a0v, 0, 0, 0);
            a1v = __builtin_amdgcn_mfma_f32_16x16x32_bf16(*(const short8*)(w1b + 288),  y9,  a1v, 0, 0, 0);
            a0v = __builtin_amdgcn_mfma_f32_16x16x32_bf16(*(const short8*)(w0b + 320),  y10, a0v, 0, 0, 0);
            a1v = __builtin_amdgcn_mfma_f32_16x16x32_bf16(*(const short8*)(w1b + 320),  y10, a1v, 0, 0, 0);
            a0v = __builtin_amdgcn_mfma_f32_16x16x32_bf16(*(const short8*)(w0b + 352),  y11, a0v, 0, 0, 0);
            a1v = __builtin_amdgcn_mfma_f32_16x16x32_bf16(*(const short8*)(w1b + 352),  y11, a1v, 0, 0, 0);
            a0v = __builtin_amdgcn_mfma_f32_16x16x32_bf16(*(const short8*)(w0b + 384),  y12, a0v, 0, 0, 0);
            a1v = __builtin_amdgcn_mfma_f32_16x16x32_bf16(*(const short8*)(w1b + 384),  y12, a1v, 0, 0, 0);
            a0v = __builtin_amdgcn_mfma_f32_16x16x32_bf16(*(const short8*)(w0b + 416),  y13, a0v, 0, 0, 0);
            a1v = __builtin_amdgcn_mfma_f32_16x16x32_bf16(*(const short8*)(w1b + 416),  y13, a1v, 0, 0, 0);
            a0v = __builtin_amdgcn_mfma_f32_16x16x32_bf16(*(const short8*)(w0b + 448),  y14, a0v, 0, 0, 0);
            a1v = __builtin_amdgcn_mfma_f32_16x16x32_bf16(*(const short8*)(w1b + 448),  y14, a1v, 0, 0, 0);
            a0v = __builtin_amdgcn_mfma_f32_16x16x32_bf16(*(const short8*)(w0b + 480),  y15, a0v, 0, 0, 0);
            a1v = __builtin_amdgcn_mfma_f32_16x16x32_bf16(*(const short8*)(w1b + 480),  y15, a1v, 0, 0, 0);
        }
        float4v bval0 = *(const float4v*)&bb[quad * 4];
        float4v bval1 = *(const float4v*)&bb[16 + quad * 4];
        if (role == 0) {
#pragma unroll
            for (int r = 0; r < 4; ++r) {
                Ut[quad * 4 + r][g * 16 + lm]      = f2bf(sc * (a0v[r] + bval0[r] - bf2f(vv0[r])));
                Ut[16 + quad * 4 + r][g * 16 + lm] = f2bf(sc * (a1v[r] + bval1[r] - bf2f(vv1[r])));
            }
        }
        __syncthreads();   // B2: Ut ready

        const size_t lbase = ((size_t)(batch * 32 + c)) * 4096 + (size_t)(g * 16 + lm) * 64;

        // (c) G^T: global Linv loads issued first, then LDS frag reads
        {
            short8 l0 = *(const short8*)(Linv + lbase + quad * 8);
            short8 l1 = *(const short8*)(Linv + lbase + 32 + quad * 8);
            short8 a0 = *(const short8*)&Ut[role * 16 + lm][quad * 8];
            short8 a1 = *(const short8*)&Ut[role * 16 + lm][32 + quad * 8];
            float4v accG = (float4v){0,0,0,0};
            accG = __builtin_amdgcn_mfma_f32_16x16x32_bf16(a0, l0, accG, 0, 0, 0);
            accG = __builtin_amdgcn_mfma_f32_16x16x32_bf16(a1, l1, accG, 0, 0, 0);
#pragma unroll
            for (int r = 0; r < 4; ++r)
                Gt[role * 16 + quad * 4 + r][g * 16 + lm] = f2bf(accG[r]);
        }
        __syncthreads();   // B3: Gt ready

        short8 agA0 = *(const short8*)&Gt[lm][quad * 8];
        short8 agA1 = *(const short8*)&Gt[lm][32 + quad * 8];
        short8 agB0 = *(const short8*)&Gt[16 + lm][quad * 8];
        short8 agB1 = *(const short8*)&Gt[16 + lm][32 + quad * 8];

        // (d) role-1 waves: O += Gt . Mp + b ; store both row halves
        if (role == 1) {
            short8 m0f = *(const short8*)(Mp + lbase + quad * 8);
            short8 m1f = *(const short8*)(Mp + lbase + 32 + quad * 8);
            a0v = __builtin_amdgcn_mfma_f32_16x16x32_bf16(agA0, m0f, a0v, 0, 0, 0);
            a0v = __builtin_amdgcn_mfma_f32_16x16x32_bf16(agA1, m1f, a0v, 0, 0, 0);
            a1v = __builtin_amdgcn_mfma_f32_16x16x32_bf16(agB0, m0f, a1v, 0, 0, 0);
            a1v = __builtin_amdgcn_mfma_f32_16x16x32_bf16(agB1, m1f, a1v, 0, 0, 0);
            float4v ov0, ov1;
#pragma unroll
            for (int r = 0; r < 4; ++r) { ov0[r] = a0v[r] + bval0[r]; ov1[r] = a1v[r] + bval1[r]; }
            *(float4v*)(out + tok * 1024 + r0 + quad * 4)      = ov0;
            *(float4v*)(out + tok * 1024 + r0 + 16 + quad * 4) = ov1;
        }

        // (e) W += Gt . Kt-contraction: ALL 16 loads issued up-front, then MFMAs
        {
            const unsigned short* kp0 = KtB + (size_t)((w +  0) * 16 + lm) * 2048 + c * 64 + quad * 8;
            const unsigned short* kp1 = KtB + (size_t)((w +  8) * 16 + lm) * 2048 + c * 64 + quad * 8;
            const unsigned short* kp2 = KtB + (size_t)((w + 16) * 16 + lm) * 2048 + c * 64 + quad * 8;
            const unsigned short* kp3 = KtB + (size_t)((w + 24) * 16 + lm) * 2048 + c * 64 + quad * 8;
            const unsigned short* kp4 = KtB + (size_t)((w + 32) * 16 + lm) * 2048 + c * 64 + quad * 8;
            const unsigned short* kp5 = KtB + (size_t)((w + 40) * 16 + lm) * 2048 + c * 64 + quad * 8;
            const unsigned short* kp6 = KtB + (size_t)((w + 48) * 16 + lm) * 2048 + c * 64 + quad * 8;
            const unsigned short* kp7 = KtB + (size_t)((w + 56) * 16 + lm) * 2048 + c * 64 + quad * 8;
            short8 e0  = *(const short8*)(kp0);
            short8 e1  = *(const short8*)(kp0 + 32);
            short8 e2  = *(const short8*)(kp1);
            short8 e3  = *(const short8*)(kp1 + 32);
            short8 e4  = *(const short8*)(kp2);
            short8 e5  = *(const short8*)(kp2 + 32);
            short8 e6  = *(const short8*)(kp3);
            short8 e7  = *(const short8*)(kp3 + 32);
            short8 e8  = *(const short8*)(kp4);
            short8 e9  = *(const short8*)(kp4 + 32);
            short8 e10 = *(const short8*)(kp5);
            short8 e11 = *(const short8*)(kp5 + 32);
            short8 e12 = *(const short8*)(kp6);
            short8 e13 = *(const short8*)(kp6 + 32);
            short8 e14 = *(const short8*)(kp7);
            short8 e15 = *(const short8*)(kp7 + 32);
            acc_w[0][0] = __builtin_amdgcn_mfma_f32_16x16x32_bf16(agA0, e0,  acc_w[0][0], 0, 0, 0);
            acc_w[0][0] = __builtin_amdgcn_mfma_f32_16x16x32_bf16(agA1, e1,  acc_w[0][0], 0, 0, 0);
            acc_w[1][0] = __builtin_amdgcn_mfma_f32_16x16x32_bf16(agB0, e0,  acc_w[1][0], 0, 0, 0);
            acc_w[1][0] = __builtin_amdgcn_mfma_f32_16x16x32_bf16(agB1, e1,  acc_w[1][0], 0, 0, 0);
            acc_w[0][1] = __builtin_amdgcn_mfma_f32_16x16x32_bf16(agA0, e2,  acc_w[0][1], 0, 0, 0);
            acc_w[0][1] = __builtin_amdgcn_mfma_f32_16x16x32_bf16(agA1, e3,  acc_w[0][1], 0, 0, 0);
            acc_w[1][1] = __builtin_amdgcn_mfma_f32_16x16x32_bf16(agB0, e2,  acc_w[1][1], 0, 0, 0);
            acc_w[1][1] = __builtin_amdgcn_mfma_f32_16x16x32_bf16(agB1, e3,  acc_w[1][1], 0, 0, 0);
            acc_w[0][2] = __builtin_amdgcn_mfma_f32_16x16x32_bf16(agA0, e4,  acc_w[0][2], 0, 0, 0);
            acc_w[0][2] = __builtin_amdgcn_mfma_f32_16x16x32_bf16(agA1, e5,  acc_w[0][2], 0, 0, 0);
            acc_w[1][2] = __builtin_amdgcn_mfma_f32_16x16x32_bf16(agB0, e4,  acc_w[1][2], 0, 0, 0);
            acc_w[1][2] = __builtin_amdgcn_mfma_f32_16x16x32_bf16(agB1, e5,  acc_w[1][2], 0, 0, 0);
            acc_w[0][3] = __builtin_amdgcn_mfma_f32_16x16x32_bf16(agA0, e6,  acc_w[0][3], 0, 0, 0);
            acc_w[0][3] = __builtin_amdgcn_mfma_f32_16x16x32_bf16(agA1, e7,  acc_w[0][3], 0, 0, 0);
            acc_w[1][3] = __builtin_amdgcn_mfma_f32_16x16x32_bf16(agB0, e6,  acc_w[1][3], 0, 0, 0);
            acc_w[1][3] = __builtin_amdgcn_mfma_f32_16x16x32_bf16(agB1, e7,  acc_w[1][3], 0, 0, 0);
            acc_w[0][4] = __builtin_amdgcn_mfma_f32_16x16x32_bf16(agA0, e8,  acc_w[0][4], 0, 0, 0);
            acc_w[0][4] = __builtin_amdgcn_mfma_f32_16x16x32_bf16(agA1, e9,  acc_w[0][4], 0, 0, 0);
            acc_w[1][4] = __builtin_amdgcn_mfma_f32_16x16x32_bf16(agB0, e8,  acc_w[1][4], 0, 0, 0);
            acc_w[1][4] = __builtin_amdgcn_mfma_f32_16x16x32_bf16(agB1, e9,  acc_w[1][4], 0, 0, 0);
            acc_w[0][5] = __builtin_amdgcn_mfma_f32_16x16x32_bf16(agA0, e10, acc_w[0][5], 0, 0, 0);
            acc_w[0][5] = __builtin_amdgcn_mfma_f32_16x16x32_bf16(agA1, e11, acc_w[0][5], 0, 0, 0);
            acc_w[1][5] = __builtin_amdgcn_mfma_f32_16x16x32_bf16(agB0, e10, acc_w[1][5], 0, 0, 0);
            acc_w[1][5] = __builtin_amdgcn_mfma_f32_16x16x32_bf16(agB1, e11, acc_w[1][5], 0, 0, 0);
            acc_w[0][6] = __builtin_amdgcn_mfma_f32_16x16x32_bf16(agA0, e12, acc_w[0][6], 0, 0, 0);
            acc_w[0][6] = __builtin_amdgcn_mfma_f32_16x16x32_bf16(agA1, e13, acc_w[0][6], 0, 0, 0);
            acc_w[1][6] = __builtin_amdgcn_mfma_f32_16x16x32_bf16(agB0, e12, acc_w[1][6], 0, 0, 0);
            acc_w[1][6] = __builtin_amdgcn_mfma_f32_16x16x32_bf16(agB1, e13, acc_w[1][6], 0, 0, 0);
            acc_w[0][7] = __builtin_amdgcn_mfma_f32_16x16x32_bf16(agA0, e14, acc_w[0][7], 0, 0, 0);
            acc_w[0][7] = __builtin_amdgcn_mfma_f32_16x16x32_bf16(agA1, e15, acc_w[0][7], 0, 0, 0);
            acc_w[1][7] = __builtin_amdgcn_mfma_f32_16x16x32_bf16(agB0, e14, acc_w[1][7], 0, 0, 0);
            acc_w[1][7] = __builtin_amdgcn_mfma_f32_16x16x32_bf16(agB1, e15, acc_w[1][7], 0, 0, 0);
        }

        // (f) bias update: wave 0, 2 lanes per row + shuffle reduce
        if (w == 0) {
            int row = lane >> 1, part = lane & 1;
            float s = 0.f;
#pragma unroll
            for (int t = 0; t < 32; ++t) s += bf2f(Gt[row][part * 32 + t]);
            s += __shfl_xor(s, 1);
            if (part == 0) bb[row] -= LR * s;
        }
        __syncthreads();   // B4: end-of-chunk
    }
}

// ---------------------------------------------------------------------------
extern "C" void kernel_launch(void* const* d_in, const int* in_sizes, int n_in,
                              void* d_out, int out_size, void* d_ws, size_t ws_size,
                              hipStream_t stream) {
    (void)in_sizes; (void)n_in; (void)out_size;
    const float* in_seq = (const float*)d_in[0];
    const float* thK    = (const float*)d_in[1];
    const float* thV    = (const float*)d_in[2];
    const float* thQ    = (const float*)d_in[3];
    const float* W0     = (const float*)d_in[4];
    const float* b0     = (const float*)d_in[5];
    float* out = (float*)d_out;

    unsigned short* ws = (unsigned short*)d_ws;
    unsigned short* Kf   = ws;                                  // 32 MB (frag-major)
    unsigned short* Vp   = ws + (size_t)16384 * 1024;           // 32 MB (row-major)
    unsigned short* Qf   = ws + (size_t)2 * 16384 * 1024;       // 32 MB (frag-major)
    unsigned short* Ktp  = ws + (size_t)3 * 16384 * 1024;       // 32 MB
    unsigned short* Linv = ws + (size_t)4 * 16384 * 1024;       // 2 MB
    unsigned short* Mpp  = Linv + (size_t)8 * 32 * 4096;        // 2 MB
    unsigned short* Abf  = Mpp + (size_t)8 * 32 * 4096;         // 32 MB (pre-cast A)
    unsigned short* Tbf  = Abf + (size_t)16384 * 1024;          // 6 MB  (pre-cast thetas)

    const size_t need_shorts = (size_t)4 * 16384 * 1024 + 2 * (size_t)8 * 32 * 4096
                             + (size_t)16384 * 1024 + (size_t)3 * 1024 * 1024;

    if (ws_size >= need_shorts * 2) {
        cast_all<<<2432, 256, 0, stream>>>(in_seq, thK, thV, thQ, Abf, Tbf);
        dim3 g1(16384 / 128, 1024 / 128);
        proj128_bf<<<g1, 512, 0, stream>>>(Abf, Tbf, Kf, Vp, Qf, Ktp);
    } else {
        dim3 g1f(16384 / 64, 1024 / 64);
        proj_gemm<<<g1f, 256, 0, stream>>>(in_seq, thK, thV, thQ, Kf, Vp, Qf, Ktp);
    }

    precomp<<<256, 256, 0, stream>>>(Kf, Qf, Linv, Mpp);

    ttt_chunk<<<256, 512, 0, stream>>>(Kf, Vp, Qf, Ktp, Linv, Mpp, W0, b0, out);
}